// Round 6
// baseline (278.120 us; speedup 1.0000x reference)
//
#include <hip/hip_runtime.h>

typedef unsigned short ushort_t;
typedef __bf16 bf16x8 __attribute__((ext_vector_type(8)));
typedef float floatx4 __attribute__((ext_vector_type(4)));
typedef float floatx16 __attribute__((ext_vector_type(16)));
typedef unsigned int uint32x2 __attribute__((ext_vector_type(2)));
typedef unsigned int uint32x4 __attribute__((ext_vector_type(4)));
typedef float float32x4 __attribute__((ext_vector_type(4)));

#define B_WIN 192
#define NTOK 256
#define CDIM 256
#define NHEAD 8
#define HDIM 32
#define NWIN 64
#define MROWS (B_WIN * NTOK)   // 49152
#define LOG2E 1.4426950408889634f

__device__ __forceinline__ float uasf(unsigned int u) {
  float f; __builtin_memcpy(&f, &u, 4); return f;
}
__device__ __forceinline__ ushort_t f2bf(float f) {
  unsigned int u; __builtin_memcpy(&u, &f, 4);
  u = (u + 0x7fffu + ((u >> 16) & 1u)) >> 16;
  return (ushort_t)u;
}
__device__ __forceinline__ bf16x8 ldg8(const ushort_t* p) {
  return *reinterpret_cast<const bf16x8*>(p);
}
__device__ __forceinline__ void async_copy16(const void* g, void* l) {
  __builtin_amdgcn_global_load_lds(
      (const __attribute__((address_space(1))) unsigned int*)g,
      (__attribute__((address_space(3))) unsigned int*)l, 16, 0, 0);
}
__device__ __forceinline__ float fexp2(float x) {
  return __builtin_amdgcn_exp2f(x);
}
__device__ __forceinline__ unsigned pkbf(float a, float b) {
  return (unsigned)f2bf(a) | ((unsigned)f2bf(b) << 16);
}
__device__ __forceinline__ void plswap(unsigned& a, unsigned& b) {
  auto r = __builtin_amdgcn_permlane32_swap(a, b, false, false);
  a = r[0]; b = r[1];
}
// non-temporal (L2-bypassing, nt flag) stores -- protect L2-resident operands
__device__ __forceinline__ void ntst_us(ushort_t* p, ushort_t v) {
  __builtin_nontemporal_store(v, p);
}
__device__ __forceinline__ void ntst_u2(void* p, uint32x2 v) {
  __builtin_nontemporal_store(v, (uint32x2*)p);
}
__device__ __forceinline__ void ntst_u4(void* p, uint32x4 v) {
  __builtin_nontemporal_store(v, (uint32x4*)p);
}
__device__ __forceinline__ void ntst_f(float* p, float v) {
  __builtin_nontemporal_store(v, p);
}
__device__ __forceinline__ float32x4 ntld_f4(const float* p) {
  return __builtin_nontemporal_load((const float32x4*)p);
}

// ---------------- kernel 0a: fp32 -> bf16 conversion (8 elems/thread) -------
__global__ __launch_bounds__(256) void cvt_f32_bf16(const float* __restrict__ src,
                                                    ushort_t* __restrict__ dst, int n8) {
  int t = blockIdx.x * 256 + threadIdx.x;
  if (t >= n8) return;
  const float* s = src + (size_t)t * 8;
  float32x4 v0 = ntld_f4(s), v1 = ntld_f4(s + 4);
  union { ushort_t u[8]; uint32x4 v; } pk;
  pk.u[0] = f2bf(v0[0]); pk.u[1] = f2bf(v0[1]); pk.u[2] = f2bf(v0[2]); pk.u[3] = f2bf(v0[3]);
  pk.u[4] = f2bf(v1[0]); pk.u[5] = f2bf(v1[1]); pk.u[6] = f2bf(v1[2]); pk.u[7] = f2bf(v1[3]);
  ntst_u4(dst + (size_t)t * 8, pk.v);
}

// ---------------- kernel 0b: fp32 weights -> bf16 MFMA-TILED ----------------
__global__ __launch_bounds__(256) void cvt_tile_w(const float* __restrict__ src,
                                                  ushort_t* __restrict__ dst, int n) {
  int t = blockIdx.x * 256 + threadIdx.x;
  if (t >= n) return;                       // n = NC*32 threads, 8 k-elems each
  int col = t >> 5;
  int kk = (t & 31) * 8;
  const float* s = src + (size_t)col * 256 + kk;
  float32x4 v0 = ntld_f4(s), v1 = ntld_f4(s + 4);
  union { ushort_t u[8]; uint32x4 v; } pk;
  pk.u[0] = f2bf(v0[0]); pk.u[1] = f2bf(v0[1]); pk.u[2] = f2bf(v0[2]); pk.u[3] = f2bf(v0[3]);
  pk.u[4] = f2bf(v1[0]); pk.u[5] = f2bf(v1[1]); pk.u[6] = f2bf(v1[2]); pk.u[7] = f2bf(v1[3]);
  size_t base = (size_t)(((col >> 4) * 8 + (kk >> 5)) * 512 + ((kk >> 3) & 3) * 128 + (col & 15) * 8);
  ntst_u4(dst + base, pk.v);
}

// ---------------- kernel 1a: mask -> 32x32 C/D-fragment order, *LOG2E -------
// slab per win: [8 qt][8 kb][2 plane][64 lane][8 regs] bf16 = 65536 elems
__global__ __launch_bounds__(256) void mask_prep(const float* __restrict__ mask,
                                                 ushort_t* __restrict__ mf) {
  const int win = blockIdx.x;      // 0..63
  const int qt = blockIdx.y;       // 0..7
  const int kb = blockIdx.z;       // 0..7
  const int l = threadIdx.x & 63;
  const int rg = threadIdx.x >> 6; // reg group 0..3
  const int tq = qt * 32 + (l & 31);
  const int hl = l >> 5;
  const int tk0 = kb * 32 + rg * 8 + hl * 4;
  const float32x4 mv = ntld_f4(mask + (size_t)win * 65536 + tq * 256 + tk0);
  union { ushort_t u[4]; uint32x2 w; } pk;
  pk.u[0] = f2bf(mv[0] * LOG2E); pk.u[1] = f2bf(mv[1] * LOG2E);
  pk.u[2] = f2bf(mv[2] * LOG2E); pk.u[3] = f2bf(mv[3] * LOG2E);
  size_t base = ((size_t)((qt * 8 + kb) * 2 + (rg >> 1))) * 512 + l * 8 + (rg & 1) * 4;
  ntst_u2(mf + ((size_t)win << 16) + base, pk.w);
}

// ---------------- kernel 1b: rel-pos bias -> fragment order, *LOG2E ---------
// slab per head: [8 qt][8 kb][2 plane][64 lane][8 regs] bf16 = 65536 elems
__global__ __launch_bounds__(256) void bias_prep(const int* __restrict__ idx,
                                                 const float* __restrict__ table,
                                                 ushort_t* __restrict__ bf) {
  const int qt = blockIdx.x;       // 0..7
  const int kb = blockIdx.y;       // 0..7
  const int l = threadIdx.x & 63;
  const int rg = threadIdx.x >> 6;
  const int tq = qt * 32 + (l & 31);
  const int hl = l >> 5;
  const int tk0 = kb * 32 + rg * 8 + hl * 4;
  const int4 ids = *reinterpret_cast<const int4*>(idx + tq * 256 + tk0);
  const int idarr[4] = {ids.x, ids.y, ids.z, ids.w};
  float v[8][4];
  #pragma unroll
  for (int r2 = 0; r2 < 4; ++r2) {
    const float* tr = table + (size_t)idarr[r2] * 8;
    float4 t0 = *reinterpret_cast<const float4*>(tr);
    float4 t1 = *reinterpret_cast<const float4*>(tr + 4);
    v[0][r2] = t0.x * LOG2E; v[1][r2] = t0.y * LOG2E;
    v[2][r2] = t0.z * LOG2E; v[3][r2] = t0.w * LOG2E;
    v[4][r2] = t1.x * LOG2E; v[5][r2] = t1.y * LOG2E;
    v[6][r2] = t1.z * LOG2E; v[7][r2] = t1.w * LOG2E;
  }
  size_t base = ((size_t)((qt * 8 + kb) * 2 + (rg >> 1))) * 512 + l * 8 + (rg & 1) * 4;
  #pragma unroll
  for (int h = 0; h < 8; ++h) {
    union { ushort_t u[4]; uint32x2 w; } pk;
    pk.u[0] = f2bf(v[h][0]); pk.u[1] = f2bf(v[h][1]);
    pk.u[2] = f2bf(v[h][2]); pk.u[3] = f2bf(v[h][3]);
    ntst_u2(bf + ((size_t)h << 16) + base, pk.w);
  }
}

// ---------------- kernel 2: QKV GEMM, XCD-swizzled, nt-store epilogue -------
// Each XCD owns 48 contiguous row-tiles (3.1 MB of A < 4 MB L2) across all
// col-tiles. Epilogue stores bypass L2 (nt) so A stays resident -> A re-reads
// are L2 hits instead of HBM-latency misses.
__global__ __launch_bounds__(256) void qkv_gemm(
    const ushort_t* __restrict__ x, const ushort_t* __restrict__ wt,
    const float* __restrict__ qkvb, ushort_t* __restrict__ qws,
    ushort_t* __restrict__ kws, ushort_t* __restrict__ vtws) {
  const int lane = threadIdx.x & 63;
  const int wv = threadIdx.x >> 6;
  const int ln = lane & 15, qd = lane >> 4;
  const int b = blockIdx.x;                 // 0..2303
  const int xcd = b & 7, lb = b >> 3;       // lb 0..287
  const int rtile = xcd * 48 + (lb % 48);   // 0..383
  const int ctile = lb / 48;                // 0..5
  const int row0 = rtile * 128 + (wv >> 1) * 64;
  const int col0 = ctile * 128;
  const int colw = col0 + (wv & 1) * 64;

  floatx4 acc[4][4];
  #pragma unroll
  for (int rt = 0; rt < 4; ++rt)
    #pragma unroll
    for (int ct = 0; ct < 4; ++ct)
      acc[rt][ct] = floatx4{0.f, 0.f, 0.f, 0.f};

  const ushort_t* ap = x + (size_t)(row0 + ln) * 256 + qd * 8;
  const ushort_t* bp = wt + (size_t)col0 * 256 + (wv & 1) * 16384 + qd * 128 + ln * 8;
  bf16x8 abuf[2][4], bbuf[2][4];
  #pragma unroll
  for (int t = 0; t < 4; ++t) {
    abuf[0][t] = ldg8(ap + t * 16 * 256);
    abuf[1][t] = ldg8(ap + t * 16 * 256 + 32);
    bbuf[0][t] = ldg8(bp + (t * 8 + 0) * 512);
    bbuf[1][t] = ldg8(bp + (t * 8 + 1) * 512);
  }

  #pragma unroll
  for (int kt = 0; kt < 8; ++kt) {
    #pragma unroll
    for (int rt = 0; rt < 4; ++rt)
      #pragma unroll
      for (int ct = 0; ct < 4; ++ct)
        acc[rt][ct] = __builtin_amdgcn_mfma_f32_16x16x32_bf16(abuf[kt & 1][rt], bbuf[kt & 1][ct],
                                                              acc[rt][ct], 0, 0, 0);
    if (kt < 6) {
      #pragma unroll
      for (int t = 0; t < 4; ++t) {
        abuf[kt & 1][t] = ldg8(ap + t * 16 * 256 + (kt + 2) * 32);
        bbuf[kt & 1][t] = ldg8(bp + (t * 8 + kt + 2) * 512);
      }
    }
  }

  const int s = colw >> 8;  // 0=q, 1=k, 2=v (uniform per wave)
  const float SCLQ = 0.17677669529663687f * LOG2E;  // 1/sqrt(32) * log2(e)
  #pragma unroll
  for (int ct = 0; ct < 4; ++ct) {
    int colg = colw + ct * 16 + ln;
    float bcol = qkvb[colg];
    int cs = colg & 255;
    int h = cs >> 5, d = cs & 31;
    int dslice = d >> 4, hh = (d >> 3) & 1, j = d & 7;
    #pragma unroll
    for (int rt = 0; rt < 4; ++rt) {
      int rbase = row0 + rt * 16 + qd * 4;
      int bwin = rbase >> 8, tok0 = rbase & 255;
      size_t slab = (size_t)(bwin * 8 + h) * 8192;
      if (s == 2) {
        int kt2 = tok0 >> 4, h2 = (tok0 >> 3) & 1, jj = tok0 & 7;
        union { ushort_t u[4]; uint32x2 v; } pk;
        #pragma unroll
        for (int i = 0; i < 4; ++i) pk.u[i] = f2bf(acc[rt][ct][i] + bcol);
        ntst_u2(vtws + slab + kt2 * 512 + h2 * 256 + d * 8 + jj, pk.v);
      } else {
        int blk = tok0 >> 5, c0 = tok0 & 31;
        size_t base = slab + (size_t)((blk * 2 + dslice) * 512 + hh * 256 + c0 * 8 + j);
        if (s == 0) {
          #pragma unroll
          for (int i = 0; i < 4; ++i)
            ntst_us(qws + base + i * 8, f2bf((acc[rt][ct][i] + bcol) * SCLQ));
        } else {
          #pragma unroll
          for (int i = 0; i < 4; ++i)
            ntst_us(kws + base + i * 8, f2bf(acc[rt][ct][i] + bcol));
        }
      }
    }
  }
}

// ---------------- kernel 3: windowed attention, 32x32 MFMA ------------------
// 8 waves x 32 q-rows. Swapped QK^T (A=K, B=Q); C-init = mask_frag + bias_frag
// (both bf16, pre-scaled by log2e); hardware exp2, no max pass;
// P->A-frag via RTNE pack + permlane32_swap. nt-store output.
__global__ __launch_bounds__(512, 4) void attn_kernel(
    const ushort_t* __restrict__ qws, const ushort_t* __restrict__ kws,
    const ushort_t* __restrict__ vtws, const ushort_t* __restrict__ mf,
    const ushort_t* __restrict__ bfr, ushort_t* __restrict__ aows) {
  __shared__ __align__(16) ushort_t lds_kv[16384];   // K 16KB | V 16KB
  __shared__ float inv_lds[256];                     // 32 per wave
  const int lane = threadIdx.x & 63;
  const int wv = threadIdx.x >> 6;
  const int t = blockIdx.x;
  const int batch = t % 3;
  const int wh = t / 3;
  const int win = wh >> 3, h = wh & 7;
  const int bwin = batch * 64 + win;
  const int bh = bwin * 8 + h;

  {
    const char* kg = (const char*)(kws + (size_t)bh * 8192);
    const char* vg = (const char*)(vtws + (size_t)bh * 8192);
    #pragma unroll
    for (int r = 0; r < 2; ++r) {
      int off = r * 8192 + wv * 1024;
      async_copy16(kg + off + lane * 16, (char*)lds_kv + off);
      async_copy16(vg + off + lane * 16, (char*)lds_kv + 16384 + off);
    }
  }
  __syncthreads();

  const int qt = wv;            // 32-token q tile per wave
  const int hl = lane >> 5;
  const ushort_t* qb = qws + (size_t)bh * 8192 + qt * 1024 + lane * 8;
  const bf16x8 qf0 = ldg8(qb);          // dslice 0
  const bf16x8 qf1 = ldg8(qb + 512);    // dslice 1
  const ushort_t* mp = mf + ((size_t)win << 16) + qt * 8192 + lane * 8;
  const ushort_t* cp = bfr + ((size_t)h << 16) + qt * 8192 + lane * 8;

  floatx16 o;
  #pragma unroll
  for (int i = 0; i < 16; ++i) o[i] = 0.f;
  float ss0 = 0.f, ss1 = 0.f, ss2 = 0.f, ss3 = 0.f;

  #pragma unroll
  for (int kb = 0; kb < 8; ++kb) {
    // C-init = mask + bias (both fragment-ordered bf16, pre-scaled by log2e)
    const uint4 m0 = *reinterpret_cast<const uint4*>(mp + kb * 1024);
    const uint4 m1 = *reinterpret_cast<const uint4*>(mp + kb * 1024 + 512);
    const uint4 c0 = *reinterpret_cast<const uint4*>(cp + kb * 1024);
    const uint4 c1 = *reinterpret_cast<const uint4*>(cp + kb * 1024 + 512);
    floatx16 st;
    st[0]  = uasf(m0.x << 16) + uasf(c0.x << 16);
    st[1]  = uasf(m0.x & 0xffff0000u) + uasf(c0.x & 0xffff0000u);
    st[2]  = uasf(m0.y << 16) + uasf(c0.y << 16);
    st[3]  = uasf(m0.y & 0xffff0000u) + uasf(c0.y & 0xffff0000u);
    st[4]  = uasf(m0.z << 16) + uasf(c0.z << 16);
    st[5]  = uasf(m0.z & 0xffff0000u) + uasf(c0.z & 0xffff0000u);
    st[6]  = uasf(m0.w << 16) + uasf(c0.w << 16);
    st[7]  = uasf(m0.w & 0xffff0000u) + uasf(c0.w & 0xffff0000u);
    st[8]  = uasf(m1.x << 16) + uasf(c1.x << 16);
    st[9]  = uasf(m1.x & 0xffff0000u) + uasf(c1.x & 0xffff0000u);
    st[10] = uasf(m1.y << 16) + uasf(c1.y << 16);
    st[11] = uasf(m1.y & 0xffff0000u) + uasf(c1.y & 0xffff0000u);
    st[12] = uasf(m1.z << 16) + uasf(c1.z << 16);
    st[13] = uasf(m1.z & 0xffff0000u) + uasf(c1.z & 0xffff0000u);
    st[14] = uasf(m1.w << 16) + uasf(c1.w << 16);
    st[15] = uasf(m1.w & 0xffff0000u) + uasf(c1.w & 0xffff0000u);

    // QK^T: S^T tile (rows = k-tokens kb*32.., cols = q-tokens qt*32..)
    const bf16x8 kf0 = *reinterpret_cast<const bf16x8*>(&lds_kv[(kb * 2 + 0) * 512 + lane * 8]);
    const bf16x8 kf1 = *reinterpret_cast<const bf16x8*>(&lds_kv[(kb * 2 + 1) * 512 + lane * 8]);
    st = __builtin_amdgcn_mfma_f32_32x32x16_bf16(kf0, qf0, st, 0, 0, 0);
    st = __builtin_amdgcn_mfma_f32_32x32x16_bf16(kf1, qf1, st, 0, 0, 0);

    // exp2 (already in log2 domain) + partial sums (4 chains to break dep)
    #pragma unroll
    for (int i = 0; i < 16; i += 4) {
      float e0 = fexp2(st[i]);     st[i]     = e0; ss0 += e0;
      float e1 = fexp2(st[i + 1]); st[i + 1] = e1; ss1 += e1;
      float e2 = fexp2(st[i + 2]); st[i + 2] = e2; ss2 += e2;
      float e3 = fexp2(st[i + 3]); st[i + 3] = e3; ss3 += e3;
    }

    // pack P->bf16 pairs (RTNE); assemble PV A-frags via half-swap
    unsigned p0 = pkbf(st[0], st[1]),   p1 = pkbf(st[2], st[3]);
    unsigned p2 = pkbf(st[4], st[5]),   p3 = pkbf(st[6], st[7]);
    unsigned p4 = pkbf(st[8], st[9]),   p5 = pkbf(st[10], st[11]);
    unsigned p6 = pkbf(st[12], st[13]), p7 = pkbf(st[14], st[15]);
    plswap(p0, p2);   // kt even: w0 = p0, w2 = p2
    plswap(p1, p3);   //          w1 = p1, w3 = p3
    plswap(p4, p6);   // kt odd
    plswap(p5, p7);
    union { unsigned u[4]; bf16x8 v; } afe, afo;
    afe.u[0] = p0; afe.u[1] = p1; afe.u[2] = p2; afe.u[3] = p3;
    afo.u[0] = p4; afo.u[1] = p5; afo.u[2] = p6; afo.u[3] = p7;

    // PV: kt = 2kb, 2kb+1
    const bf16x8 bv0 = *reinterpret_cast<const bf16x8*>(&lds_kv[8192 + (kb * 2 + 0) * 512 + lane * 8]);
    const bf16x8 bv1 = *reinterpret_cast<const bf16x8*>(&lds_kv[8192 + (kb * 2 + 1) * 512 + lane * 8]);
    o = __builtin_amdgcn_mfma_f32_32x32x16_bf16(afe.v, bv0, o, 0, 0, 0);
    o = __builtin_amdgcn_mfma_f32_32x32x16_bf16(afo.v, bv1, o, 0, 0, 0);
  }

  float ssum = (ss0 + ss1) + (ss2 + ss3);
  ssum += __shfl_xor(ssum, 32, 64);
  const float inv = 1.0f / ssum;
  inv_lds[wv * 32 + (lane & 31)] = inv;   // lanes l and l^32 write same value
  __builtin_amdgcn_s_waitcnt(0);          // drain lgkm for own-wave LDS readback
  const float4 iv0 = *reinterpret_cast<const float4*>(&inv_lds[wv * 32 + 0 + hl * 4]);
  const float4 iv1 = *reinterpret_cast<const float4*>(&inv_lds[wv * 32 + 8 + hl * 4]);
  const float4 iv2 = *reinterpret_cast<const float4*>(&inv_lds[wv * 32 + 16 + hl * 4]);
  const float4 iv3 = *reinterpret_cast<const float4*>(&inv_lds[wv * 32 + 24 + hl * 4]);

  const int d = lane & 31;
  ushort_t* op = aows + (((size_t)bwin * 256 + qt * 32 + 4 * hl) << 8) + h * 32 + d;
  ntst_us(op + 0 * 256,  f2bf(o[0]  * iv0.x)); ntst_us(op + 1 * 256,  f2bf(o[1]  * iv0.y));
  ntst_us(op + 2 * 256,  f2bf(o[2]  * iv0.z)); ntst_us(op + 3 * 256,  f2bf(o[3]  * iv0.w));
  ntst_us(op + 8 * 256,  f2bf(o[4]  * iv1.x)); ntst_us(op + 9 * 256,  f2bf(o[5]  * iv1.y));
  ntst_us(op + 10 * 256, f2bf(o[6]  * iv1.z)); ntst_us(op + 11 * 256, f2bf(o[7]  * iv1.w));
  ntst_us(op + 16 * 256, f2bf(o[8]  * iv2.x)); ntst_us(op + 17 * 256, f2bf(o[9]  * iv2.y));
  ntst_us(op + 18 * 256, f2bf(o[10] * iv2.z)); ntst_us(op + 19 * 256, f2bf(o[11] * iv2.w));
  ntst_us(op + 24 * 256, f2bf(o[12] * iv3.x)); ntst_us(op + 25 * 256, f2bf(o[13] * iv3.y));
  ntst_us(op + 26 * 256, f2bf(o[14] * iv3.z)); ntst_us(op + 27 * 256, f2bf(o[15] * iv3.w));
}

// ---------------- kernel 4: output projection, XCD-swizzled, nt-store out ---
__global__ __launch_bounds__(256) void proj_gemm(
    const ushort_t* __restrict__ a_, const ushort_t* __restrict__ wt,
    const float* __restrict__ pb, float* __restrict__ out) {
  const int lane = threadIdx.x & 63;
  const int wv = threadIdx.x >> 6;
  const int ln = lane & 15, qd = lane >> 4;
  const int b = blockIdx.x;                 // 0..767
  const int xcd = b & 7, lb = b >> 3;       // lb 0..95
  const int rtile = xcd * 48 + (lb % 48);   // 0..383
  const int ctile = lb / 48;                // 0..1
  const int row0 = rtile * 128 + (wv >> 1) * 64;
  const int col0 = ctile * 128;
  const int colw = col0 + (wv & 1) * 64;

  floatx4 acc[4][4];
  #pragma unroll
  for (int rt = 0; rt < 4; ++rt)
    #pragma unroll
    for (int ct = 0; ct < 4; ++ct)
      acc[rt][ct] = floatx4{0.f, 0.f, 0.f, 0.f};

  const ushort_t* ap = a_ + (size_t)(row0 + ln) * 256 + qd * 8;
  const ushort_t* bp = wt + (size_t)col0 * 256 + (wv & 1) * 16384 + qd * 128 + ln * 8;
  bf16x8 abuf[2][4], bbuf[2][4];
  #pragma unroll
  for (int t = 0; t < 4; ++t) {
    abuf[0][t] = ldg8(ap + t * 16 * 256);
    abuf[1][t] = ldg8(ap + t * 16 * 256 + 32);
    bbuf[0][t] = ldg8(bp + (t * 8 + 0) * 512);
    bbuf[1][t] = ldg8(bp + (t * 8 + 1) * 512);
  }

  #pragma unroll
  for (int kt = 0; kt < 8; ++kt) {
    #pragma unroll
    for (int rt = 0; rt < 4; ++rt)
      #pragma unroll
      for (int ct = 0; ct < 4; ++ct)
        acc[rt][ct] = __builtin_amdgcn_mfma_f32_16x16x32_bf16(abuf[kt & 1][rt], bbuf[kt & 1][ct],
                                                              acc[rt][ct], 0, 0, 0);
    if (kt < 6) {
      #pragma unroll
      for (int t = 0; t < 4; ++t) {
        abuf[kt & 1][t] = ldg8(ap + t * 16 * 256 + (kt + 2) * 32);
        bbuf[kt & 1][t] = ldg8(bp + (t * 8 + kt + 2) * 512);
      }
    }
  }

  #pragma unroll
  for (int ct = 0; ct < 4; ++ct) {
    int colg = colw + ct * 16 + ln;
    float bcol = pb[colg];
    #pragma unroll
    for (int rt = 0; rt < 4; ++rt) {
      int rbase = row0 + rt * 16 + qd * 4;
      #pragma unroll
      for (int i = 0; i < 4; ++i)
        ntst_f(out + (size_t)(rbase + i) * 256 + colg, acc[rt][ct][i] + bcol);
    }
  }
}

// ---------------- launch ----------------------------------------------------
extern "C" void kernel_launch(void* const* d_in, const int* in_sizes, int n_in,
                              void* d_out, int out_size, void* d_ws, size_t ws_size,
                              hipStream_t stream) {
  const float* x      = (const float*)d_in[0];
  const float* mask   = (const float*)d_in[1];
  const float* qkv_w  = (const float*)d_in[2];
  const float* qkv_b  = (const float*)d_in[3];
  const float* proj_w = (const float*)d_in[4];
  const float* proj_b = (const float*)d_in[5];
  const float* table  = (const float*)d_in[6];
  const int*   idx    = (const int*)d_in[7];
  float* out = (float*)d_out;

  char* ws = (char*)d_ws;
  const size_t SZ = (size_t)MROWS * CDIM * 2;  // 25165824 B per bf16 buffer
  ushort_t* xbf  = (ushort_t*)(ws);
  ushort_t* qws  = (ushort_t*)(ws + SZ);       // q fragment slabs
  ushort_t* kws  = (ushort_t*)(ws + 2 * SZ);   // k fragment slabs
  ushort_t* vtws = (ushort_t*)(ws + 3 * SZ);   // v fragment slabs
  ushort_t* aows = (ushort_t*)(ws + 4 * SZ);
  ushort_t* mfws = (ushort_t*)(ws + 5 * SZ);                       // 8.4 MB mask frags
  ushort_t* bfws = (ushort_t*)(ws + 5 * SZ + 8388608);             // 1 MB bias frags
  ushort_t* wqkvbf  = (ushort_t*)(ws + 5 * SZ + 8388608 + 1048576);
  ushort_t* wprojbf = (ushort_t*)(ws + 5 * SZ + 8388608 + 1048576 + 393216);

  cvt_f32_bf16<<<dim3(6144), dim3(256), 0, stream>>>(x, xbf, 12582912 / 8);
  cvt_tile_w<<<dim3(96), dim3(256), 0, stream>>>(qkv_w, wqkvbf, 768 * 32);
  cvt_tile_w<<<dim3(32), dim3(256), 0, stream>>>(proj_w, wprojbf, 256 * 32);
  mask_prep<<<dim3(64, 8, 8), dim3(256), 0, stream>>>(mask, mfws);
  bias_prep<<<dim3(8, 8), dim3(256), 0, stream>>>(idx, table, bfws);
  qkv_gemm<<<dim3(2304), dim3(256), 0, stream>>>(xbf, wqkvbf, qkv_b, qws, kws, vtws);
  attn_kernel<<<dim3(1536), dim3(512), 0, stream>>>(qws, kws, vtws, mfws, bfws, aows);
  proj_gemm<<<dim3(768), dim3(256), 0, stream>>>(aows, wprojbf, proj_b, out);
}

// Round 7
// 250.034 us; speedup vs baseline: 1.1123x; 1.1123x over previous
//
#include <hip/hip_runtime.h>

typedef unsigned short ushort_t;
typedef __bf16 bf16x8 __attribute__((ext_vector_type(8)));
typedef float floatx4 __attribute__((ext_vector_type(4)));
typedef float floatx16 __attribute__((ext_vector_type(16)));

#define B_WIN 192
#define NTOK 256
#define CDIM 256
#define NHEAD 8
#define HDIM 32
#define NWIN 64
#define MROWS (B_WIN * NTOK)   // 49152
#define LOG2E 1.4426950408889634f

__device__ __forceinline__ float uasf(unsigned int u) {
  float f; __builtin_memcpy(&f, &u, 4); return f;
}
__device__ __forceinline__ ushort_t f2bf(float f) {
  unsigned int u; __builtin_memcpy(&u, &f, 4);
  u = (u + 0x7fffu + ((u >> 16) & 1u)) >> 16;
  return (ushort_t)u;
}
__device__ __forceinline__ bf16x8 ldg8(const ushort_t* p) {
  return *reinterpret_cast<const bf16x8*>(p);
}
__device__ __forceinline__ void async_copy16(const void* g, void* l) {
  __builtin_amdgcn_global_load_lds(
      (const __attribute__((address_space(1))) unsigned int*)g,
      (__attribute__((address_space(3))) unsigned int*)l, 16, 0, 0);
}
__device__ __forceinline__ float fexp2(float x) {
  return __builtin_amdgcn_exp2f(x);
}
__device__ __forceinline__ unsigned pkbf(float a, float b) {
  return (unsigned)f2bf(a) | ((unsigned)f2bf(b) << 16);
}
__device__ __forceinline__ void plswap(unsigned& a, unsigned& b) {
  auto r = __builtin_amdgcn_permlane32_swap(a, b, false, false);
  a = r[0]; b = r[1];
}

// ---------------- kernel 0: fp32 -> bf16 MFMA-TILED (rows x 256 cols) -------
// dst(row,col) = ((row>>4)*8 + (col>>5))*512 + ((col>>3)&3)*128 + (row&15)*8 + (col&7)
// Each 16-row x 32-col chunk is 1024 contiguous bytes; a wave's b128 frag read
// (offset qd*256 + ln*16 bytes) is lane-sequential -> conflict-free, and
// global_load_lds can stage chunks linearly. Used for x, qkv_w, proj_w.
__global__ __launch_bounds__(256) void cvt_tile_w(const float* __restrict__ src,
                                                  ushort_t* __restrict__ dst, int n) {
  int t = blockIdx.x * 256 + threadIdx.x;
  if (t >= n) return;                       // n = NROWS*32 threads, 8 col-elems each
  int row = t >> 5;
  int kk = (t & 31) * 8;
  const float4* s = reinterpret_cast<const float4*>(src + (size_t)row * 256 + kk);
  float4 v0 = s[0], v1 = s[1];
  union { ushort_t u[8]; uint4 v; } pk;
  pk.u[0] = f2bf(v0.x); pk.u[1] = f2bf(v0.y); pk.u[2] = f2bf(v0.z); pk.u[3] = f2bf(v0.w);
  pk.u[4] = f2bf(v1.x); pk.u[5] = f2bf(v1.y); pk.u[6] = f2bf(v1.z); pk.u[7] = f2bf(v1.w);
  size_t base = (size_t)(((row >> 4) * 8 + (kk >> 5)) * 512 + ((kk >> 3) & 3) * 128 + (row & 15) * 8);
  *reinterpret_cast<uint4*>(dst + base) = pk.v;
}

// ---------------- kernel 1a: mask -> 32x32 C/D-fragment order, *LOG2E -------
__global__ __launch_bounds__(256) void mask_prep(const float* __restrict__ mask,
                                                 ushort_t* __restrict__ mf) {
  const int win = blockIdx.x;      // 0..63
  const int qt = blockIdx.y;       // 0..7
  const int kb = blockIdx.z;       // 0..7
  const int l = threadIdx.x & 63;
  const int rg = threadIdx.x >> 6; // reg group 0..3
  const int tq = qt * 32 + (l & 31);
  const int hl = l >> 5;
  const int tk0 = kb * 32 + rg * 8 + hl * 4;
  const float4 mv = *reinterpret_cast<const float4*>(mask + (size_t)win * 65536 + tq * 256 + tk0);
  union { ushort_t u[4]; uint2 w; } pk;
  pk.u[0] = f2bf(mv.x * LOG2E); pk.u[1] = f2bf(mv.y * LOG2E);
  pk.u[2] = f2bf(mv.z * LOG2E); pk.u[3] = f2bf(mv.w * LOG2E);
  size_t base = ((size_t)((qt * 8 + kb) * 2 + (rg >> 1))) * 512 + l * 8 + (rg & 1) * 4;
  *reinterpret_cast<uint2*>(mf + ((size_t)win << 16) + base) = pk.w;
}

// ---------------- kernel 1b: rel-pos bias -> fragment order, *LOG2E ---------
__global__ __launch_bounds__(256) void bias_prep(const int* __restrict__ idx,
                                                 const float* __restrict__ table,
                                                 ushort_t* __restrict__ bf) {
  const int qt = blockIdx.x;       // 0..7
  const int kb = blockIdx.y;       // 0..7
  const int l = threadIdx.x & 63;
  const int rg = threadIdx.x >> 6;
  const int tq = qt * 32 + (l & 31);
  const int hl = l >> 5;
  const int tk0 = kb * 32 + rg * 8 + hl * 4;
  const int4 ids = *reinterpret_cast<const int4*>(idx + tq * 256 + tk0);
  const int idarr[4] = {ids.x, ids.y, ids.z, ids.w};
  float v[8][4];
  #pragma unroll
  for (int r2 = 0; r2 < 4; ++r2) {
    const float* tr = table + (size_t)idarr[r2] * 8;
    float4 t0 = *reinterpret_cast<const float4*>(tr);
    float4 t1 = *reinterpret_cast<const float4*>(tr + 4);
    v[0][r2] = t0.x * LOG2E; v[1][r2] = t0.y * LOG2E;
    v[2][r2] = t0.z * LOG2E; v[3][r2] = t0.w * LOG2E;
    v[4][r2] = t1.x * LOG2E; v[5][r2] = t1.y * LOG2E;
    v[6][r2] = t1.z * LOG2E; v[7][r2] = t1.w * LOG2E;
  }
  size_t base = ((size_t)((qt * 8 + kb) * 2 + (rg >> 1))) * 512 + l * 8 + (rg & 1) * 4;
  #pragma unroll
  for (int h = 0; h < 8; ++h) {
    union { ushort_t u[4]; uint2 w; } pk;
    pk.u[0] = f2bf(v[h][0]); pk.u[1] = f2bf(v[h][1]);
    pk.u[2] = f2bf(v[h][2]); pk.u[3] = f2bf(v[h][3]);
    *reinterpret_cast<uint2*>(bf + ((size_t)h << 16) + base) = pk.w;
  }
}

// ---------------- kernel 2: QKV GEMM, 2-phase global_load_lds pipeline ------
// m97/T3-minimum structure: per K-step {STAGE next k-tile to LDS dbuf (zero
// VGPR, coalesced 1KB/wave-inst) -> ds_read frags -> 16 MFMA -> one barrier}.
// A and B both pre-tiled so LDS chunks are linear and frag reads lane-seq.
__global__ __launch_bounds__(256) void qkv_gemm(
    const ushort_t* __restrict__ x, const ushort_t* __restrict__ wt,
    const float* __restrict__ qkvb, ushort_t* __restrict__ qws,
    ushort_t* __restrict__ kws, ushort_t* __restrict__ vtws) {
  __shared__ __align__(16) char lds[32768];   // A dbuf [2][8192] | B dbuf at +16384
  const int lane = threadIdx.x & 63;
  const int wv = threadIdx.x >> 6;
  const int ln = lane & 15, qd = lane >> 4;
  const int b = blockIdx.x;                 // 0..2303
  const int xcd = b & 7, lb = b >> 3;       // lb 0..287
  const int rtile = xcd * 48 + (lb % 48);   // 0..383
  const int ctile = lb / 48;                // 0..5
  const int row0 = rtile * 128 + (wv >> 1) * 64;
  const int colw = ctile * 128 + (wv & 1) * 64;

  const char* ag = (const char*)x + (size_t)rtile * 65536;   // 8 row-chunks x 8 kt x 1KB
  const char* bg = (const char*)wt + (size_t)ctile * 65536;  // 8 col-chunks x 8 kt x 1KB

  floatx4 acc[4][4];
  #pragma unroll
  for (int rt = 0; rt < 4; ++rt)
    #pragma unroll
    for (int ct = 0; ct < 4; ++ct)
      acc[rt][ct] = floatx4{0.f, 0.f, 0.f, 0.f};

  // wave wv stages chunks {2wv, 2wv+1} of A and of B for the given kt
  #define STAGE(buf, kt)                                                          \
    {                                                                             \
      _Pragma("unroll")                                                           \
      for (int c2 = 0; c2 < 2; ++c2) {                                            \
        int c = wv * 2 + c2;                                                      \
        async_copy16(ag + (((size_t)c * 8 + (kt)) << 10) + lane * 16,             \
                     lds + (buf) * 8192 + c * 1024);                              \
        async_copy16(bg + (((size_t)c * 8 + (kt)) << 10) + lane * 16,             \
                     lds + 16384 + (buf) * 8192 + c * 1024);                      \
      }                                                                           \
    }

  STAGE(0, 0);
  __syncthreads();      // drains vmcnt(0): buf0 ready

  int cur = 0;
  #pragma unroll
  for (int kt = 0; kt < 8; ++kt) {
    if (kt < 7) STAGE(cur ^ 1, kt + 1);
    const char* ab = lds + cur * 8192 + ((wv >> 1) * 4) * 1024 + qd * 256 + ln * 16;
    const char* bb = lds + 16384 + cur * 8192 + ((wv & 1) * 4) * 1024 + qd * 256 + ln * 16;
    bf16x8 a[4], bq[4];
    #pragma unroll
    for (int t = 0; t < 4; ++t) {
      a[t] = *reinterpret_cast<const bf16x8*>(ab + t * 1024);
      bq[t] = *reinterpret_cast<const bf16x8*>(bb + t * 1024);
    }
    #pragma unroll
    for (int rt = 0; rt < 4; ++rt)
      #pragma unroll
      for (int ct = 0; ct < 4; ++ct)
        acc[rt][ct] = __builtin_amdgcn_mfma_f32_16x16x32_bf16(a[rt], bq[ct],
                                                              acc[rt][ct], 0, 0, 0);
    if (kt < 7) __syncthreads();   // next buffer staged + this buffer consumed
    cur ^= 1;
  }
  #undef STAGE

  const int s = colw >> 8;  // 0=q, 1=k, 2=v (uniform per wave)
  const float SCLQ = 0.17677669529663687f * LOG2E;  // 1/sqrt(32) * log2(e)
  #pragma unroll
  for (int ct = 0; ct < 4; ++ct) {
    int colg = colw + ct * 16 + ln;
    float bcol = qkvb[colg];
    int cs = colg & 255;
    int h = cs >> 5, d = cs & 31;
    int dslice = d >> 4, hh = (d >> 3) & 1, j = d & 7;
    #pragma unroll
    for (int rt = 0; rt < 4; ++rt) {
      int rbase = row0 + rt * 16 + qd * 4;
      int bwin = rbase >> 8, tok0 = rbase & 255;
      size_t slab = (size_t)(bwin * 8 + h) * 8192;
      if (s == 2) {
        int kt2 = tok0 >> 4, h2 = (tok0 >> 3) & 1, jj = tok0 & 7;
        union { ushort_t u[4]; uint2 v; } pk;
        #pragma unroll
        for (int i = 0; i < 4; ++i) pk.u[i] = f2bf(acc[rt][ct][i] + bcol);
        *reinterpret_cast<uint2*>(vtws + slab + kt2 * 512 + h2 * 256 + d * 8 + jj) = pk.v;
      } else {
        int blk = tok0 >> 5, c0 = tok0 & 31;
        size_t base = slab + (size_t)((blk * 2 + dslice) * 512 + hh * 256 + c0 * 8 + j);
        if (s == 0) {
          #pragma unroll
          for (int i = 0; i < 4; ++i)
            qws[base + i * 8] = f2bf((acc[rt][ct][i] + bcol) * SCLQ);
        } else {
          #pragma unroll
          for (int i = 0; i < 4; ++i)
            kws[base + i * 8] = f2bf(acc[rt][ct][i] + bcol);
        }
      }
    }
  }
}

// ---------------- kernel 3: windowed attention, 32x32 MFMA ------------------
// Unchanged compute; epilogue now scatters aows in tiled-A layout so
// proj_gemm can use the 2-phase global_load_lds structure.
__global__ __launch_bounds__(512, 4) void attn_kernel(
    const ushort_t* __restrict__ qws, const ushort_t* __restrict__ kws,
    const ushort_t* __restrict__ vtws, const ushort_t* __restrict__ mf,
    const ushort_t* __restrict__ bfr, ushort_t* __restrict__ aows) {
  __shared__ __align__(16) ushort_t lds_kv[16384];   // K 16KB | V 16KB
  __shared__ float inv_lds[256];                     // 32 per wave
  const int lane = threadIdx.x & 63;
  const int wv = threadIdx.x >> 6;
  const int t = blockIdx.x;
  const int batch = t % 3;
  const int wh = t / 3;
  const int win = wh >> 3, h = wh & 7;
  const int bwin = batch * 64 + win;
  const int bh = bwin * 8 + h;

  {
    const char* kg = (const char*)(kws + (size_t)bh * 8192);
    const char* vg = (const char*)(vtws + (size_t)bh * 8192);
    #pragma unroll
    for (int r = 0; r < 2; ++r) {
      int off = r * 8192 + wv * 1024;
      async_copy16(kg + off + lane * 16, (char*)lds_kv + off);
      async_copy16(vg + off + lane * 16, (char*)lds_kv + 16384 + off);
    }
  }
  __syncthreads();

  const int qt = wv;            // 32-token q tile per wave
  const int hl = lane >> 5;
  const ushort_t* qb = qws + (size_t)bh * 8192 + qt * 1024 + lane * 8;
  const bf16x8 qf0 = ldg8(qb);          // dslice 0
  const bf16x8 qf1 = ldg8(qb + 512);    // dslice 1
  const ushort_t* mp = mf + ((size_t)win << 16) + qt * 8192 + lane * 8;
  const ushort_t* cp = bfr + ((size_t)h << 16) + qt * 8192 + lane * 8;

  floatx16 o;
  #pragma unroll
  for (int i = 0; i < 16; ++i) o[i] = 0.f;
  float ss0 = 0.f, ss1 = 0.f, ss2 = 0.f, ss3 = 0.f;

  #pragma unroll
  for (int kb = 0; kb < 8; ++kb) {
    const uint4 m0 = *reinterpret_cast<const uint4*>(mp + kb * 1024);
    const uint4 m1 = *reinterpret_cast<const uint4*>(mp + kb * 1024 + 512);
    const uint4 c0 = *reinterpret_cast<const uint4*>(cp + kb * 1024);
    const uint4 c1 = *reinterpret_cast<const uint4*>(cp + kb * 1024 + 512);
    floatx16 st;
    st[0]  = uasf(m0.x << 16) + uasf(c0.x << 16);
    st[1]  = uasf(m0.x & 0xffff0000u) + uasf(c0.x & 0xffff0000u);
    st[2]  = uasf(m0.y << 16) + uasf(c0.y << 16);
    st[3]  = uasf(m0.y & 0xffff0000u) + uasf(c0.y & 0xffff0000u);
    st[4]  = uasf(m0.z << 16) + uasf(c0.z << 16);
    st[5]  = uasf(m0.z & 0xffff0000u) + uasf(c0.z & 0xffff0000u);
    st[6]  = uasf(m0.w << 16) + uasf(c0.w << 16);
    st[7]  = uasf(m0.w & 0xffff0000u) + uasf(c0.w & 0xffff0000u);
    st[8]  = uasf(m1.x << 16) + uasf(c1.x << 16);
    st[9]  = uasf(m1.x & 0xffff0000u) + uasf(c1.x & 0xffff0000u);
    st[10] = uasf(m1.y << 16) + uasf(c1.y << 16);
    st[11] = uasf(m1.y & 0xffff0000u) + uasf(c1.y & 0xffff0000u);
    st[12] = uasf(m1.z << 16) + uasf(c1.z << 16);
    st[13] = uasf(m1.z & 0xffff0000u) + uasf(c1.z & 0xffff0000u);
    st[14] = uasf(m1.w << 16) + uasf(c1.w << 16);
    st[15] = uasf(m1.w & 0xffff0000u) + uasf(c1.w & 0xffff0000u);

    const bf16x8 kf0 = *reinterpret_cast<const bf16x8*>(&lds_kv[(kb * 2 + 0) * 512 + lane * 8]);
    const bf16x8 kf1 = *reinterpret_cast<const bf16x8*>(&lds_kv[(kb * 2 + 1) * 512 + lane * 8]);
    st = __builtin_amdgcn_mfma_f32_32x32x16_bf16(kf0, qf0, st, 0, 0, 0);
    st = __builtin_amdgcn_mfma_f32_32x32x16_bf16(kf1, qf1, st, 0, 0, 0);

    #pragma unroll
    for (int i = 0; i < 16; i += 4) {
      float e0 = fexp2(st[i]);     st[i]     = e0; ss0 += e0;
      float e1 = fexp2(st[i + 1]); st[i + 1] = e1; ss1 += e1;
      float e2 = fexp2(st[i + 2]); st[i + 2] = e2; ss2 += e2;
      float e3 = fexp2(st[i + 3]); st[i + 3] = e3; ss3 += e3;
    }

    unsigned p0 = pkbf(st[0], st[1]),   p1 = pkbf(st[2], st[3]);
    unsigned p2 = pkbf(st[4], st[5]),   p3 = pkbf(st[6], st[7]);
    unsigned p4 = pkbf(st[8], st[9]),   p5 = pkbf(st[10], st[11]);
    unsigned p6 = pkbf(st[12], st[13]), p7 = pkbf(st[14], st[15]);
    plswap(p0, p2);
    plswap(p1, p3);
    plswap(p4, p6);
    plswap(p5, p7);
    union { unsigned u[4]; bf16x8 v; } afe, afo;
    afe.u[0] = p0; afe.u[1] = p1; afe.u[2] = p2; afe.u[3] = p3;
    afo.u[0] = p4; afo.u[1] = p5; afo.u[2] = p6; afo.u[3] = p7;

    const bf16x8 bv0 = *reinterpret_cast<const bf16x8*>(&lds_kv[8192 + (kb * 2 + 0) * 512 + lane * 8]);
    const bf16x8 bv1 = *reinterpret_cast<const bf16x8*>(&lds_kv[8192 + (kb * 2 + 1) * 512 + lane * 8]);
    o = __builtin_amdgcn_mfma_f32_32x32x16_bf16(afe.v, bv0, o, 0, 0, 0);
    o = __builtin_amdgcn_mfma_f32_32x32x16_bf16(afo.v, bv1, o, 0, 0, 0);
  }

  float ssum = (ss0 + ss1) + (ss2 + ss3);
  ssum += __shfl_xor(ssum, 32, 64);
  const float inv = 1.0f / ssum;
  inv_lds[wv * 32 + (lane & 31)] = inv;
  __builtin_amdgcn_s_waitcnt(0);
  const float4 iv0 = *reinterpret_cast<const float4*>(&inv_lds[wv * 32 + 0 + hl * 4]);
  const float4 iv1 = *reinterpret_cast<const float4*>(&inv_lds[wv * 32 + 8 + hl * 4]);
  const float4 iv2 = *reinterpret_cast<const float4*>(&inv_lds[wv * 32 + 16 + hl * 4]);
  const float4 iv3 = *reinterpret_cast<const float4*>(&inv_lds[wv * 32 + 24 + hl * 4]);

  // tiled-A scatter: halfword = ((bwin*16 + 2qt + (r>>1))*8 + h)*512
  //                  + ((d>>3)&3)*128 + (8*(r&1) + 4*hl + i)*8 + (d&7)
  const int d = lane & 31;
  ushort_t* op = aows + (((size_t)(bwin * 16 + 2 * qt) * 8 + h) << 9)
                 + ((d >> 3) & 3) * 128 + hl * 32 + (d & 7);
  op[0 * 8]              = f2bf(o[0]  * iv0.x);
  op[1 * 8]              = f2bf(o[1]  * iv0.y);
  op[2 * 8]              = f2bf(o[2]  * iv0.z);
  op[3 * 8]              = f2bf(o[3]  * iv0.w);
  op[64 + 0 * 8]         = f2bf(o[4]  * iv1.x);
  op[64 + 1 * 8]         = f2bf(o[5]  * iv1.y);
  op[64 + 2 * 8]         = f2bf(o[6]  * iv1.z);
  op[64 + 3 * 8]         = f2bf(o[7]  * iv1.w);
  op[4096 + 0 * 8]       = f2bf(o[8]  * iv2.x);
  op[4096 + 1 * 8]       = f2bf(o[9]  * iv2.y);
  op[4096 + 2 * 8]       = f2bf(o[10] * iv2.z);
  op[4096 + 3 * 8]       = f2bf(o[11] * iv2.w);
  op[4096 + 64 + 0 * 8]  = f2bf(o[12] * iv3.x);
  op[4096 + 64 + 1 * 8]  = f2bf(o[13] * iv3.y);
  op[4096 + 64 + 2 * 8]  = f2bf(o[14] * iv3.z);
  op[4096 + 64 + 3 * 8]  = f2bf(o[15] * iv3.w);
}

// ---------------- kernel 4: output projection, 2-phase LDS pipeline ---------
__global__ __launch_bounds__(256) void proj_gemm(
    const ushort_t* __restrict__ a_, const ushort_t* __restrict__ wt,
    const float* __restrict__ pb, float* __restrict__ out) {
  __shared__ __align__(16) char lds[32768];
  const int lane = threadIdx.x & 63;
  const int wv = threadIdx.x >> 6;
  const int ln = lane & 15, qd = lane >> 4;
  const int b = blockIdx.x;                 // 0..767
  const int xcd = b & 7, lb = b >> 3;       // lb 0..95
  const int rtile = xcd * 48 + (lb % 48);   // 0..383
  const int ctile = lb / 48;                // 0..1
  const int row0 = rtile * 128 + (wv >> 1) * 64;
  const int colw = ctile * 128 + (wv & 1) * 64;

  const char* ag = (const char*)a_ + (size_t)rtile * 65536;
  const char* bg = (const char*)wt + (size_t)ctile * 65536;

  floatx4 acc[4][4];
  #pragma unroll
  for (int rt = 0; rt < 4; ++rt)
    #pragma unroll
    for (int ct = 0; ct < 4; ++ct)
      acc[rt][ct] = floatx4{0.f, 0.f, 0.f, 0.f};

  #define STAGE(buf, kt)                                                          \
    {                                                                             \
      _Pragma("unroll")                                                           \
      for (int c2 = 0; c2 < 2; ++c2) {                                            \
        int c = wv * 2 + c2;                                                      \
        async_copy16(ag + (((size_t)c * 8 + (kt)) << 10) + lane * 16,             \
                     lds + (buf) * 8192 + c * 1024);                              \
        async_copy16(bg + (((size_t)c * 8 + (kt)) << 10) + lane * 16,             \
                     lds + 16384 + (buf) * 8192 + c * 1024);                      \
      }                                                                           \
    }

  STAGE(0, 0);
  __syncthreads();

  int cur = 0;
  #pragma unroll
  for (int kt = 0; kt < 8; ++kt) {
    if (kt < 7) STAGE(cur ^ 1, kt + 1);
    const char* ab = lds + cur * 8192 + ((wv >> 1) * 4) * 1024 + qd * 256 + ln * 16;
    const char* bb = lds + 16384 + cur * 8192 + ((wv & 1) * 4) * 1024 + qd * 256 + ln * 16;
    bf16x8 a[4], bq[4];
    #pragma unroll
    for (int t = 0; t < 4; ++t) {
      a[t] = *reinterpret_cast<const bf16x8*>(ab + t * 1024);
      bq[t] = *reinterpret_cast<const bf16x8*>(bb + t * 1024);
    }
    #pragma unroll
    for (int rt = 0; rt < 4; ++rt)
      #pragma unroll
      for (int ct = 0; ct < 4; ++ct)
        acc[rt][ct] = __builtin_amdgcn_mfma_f32_16x16x32_bf16(a[rt], bq[ct],
                                                              acc[rt][ct], 0, 0, 0);
    if (kt < 7) __syncthreads();
    cur ^= 1;
  }
  #undef STAGE

  #pragma unroll
  for (int ct = 0; ct < 4; ++ct) {
    int colg = colw + ct * 16 + ln;
    float bcol = pb[colg];
    #pragma unroll
    for (int rt = 0; rt < 4; ++rt) {
      int rbase = row0 + rt * 16 + qd * 4;
      #pragma unroll
      for (int i = 0; i < 4; ++i)
        out[(size_t)(rbase + i) * 256 + colg] = acc[rt][ct][i] + bcol;
    }
  }
}

// ---------------- launch ----------------------------------------------------
extern "C" void kernel_launch(void* const* d_in, const int* in_sizes, int n_in,
                              void* d_out, int out_size, void* d_ws, size_t ws_size,
                              hipStream_t stream) {
  const float* x      = (const float*)d_in[0];
  const float* mask   = (const float*)d_in[1];
  const float* qkv_w  = (const float*)d_in[2];
  const float* qkv_b  = (const float*)d_in[3];
  const float* proj_w = (const float*)d_in[4];
  const float* proj_b = (const float*)d_in[5];
  const float* table  = (const float*)d_in[6];
  const int*   idx    = (const int*)d_in[7];
  float* out = (float*)d_out;

  char* ws = (char*)d_ws;
  const size_t SZ = (size_t)MROWS * CDIM * 2;  // 25165824 B per bf16 buffer
  ushort_t* xbf  = (ushort_t*)(ws);            // tiled-A x
  ushort_t* qws  = (ushort_t*)(ws + SZ);       // q fragment slabs
  ushort_t* kws  = (ushort_t*)(ws + 2 * SZ);   // k fragment slabs
  ushort_t* vtws = (ushort_t*)(ws + 3 * SZ);   // v fragment slabs
  ushort_t* aows = (ushort_t*)(ws + 4 * SZ);   // tiled-A attn output
  ushort_t* mfws = (ushort_t*)(ws + 5 * SZ);                       // 8.4 MB mask frags
  ushort_t* bfws = (ushort_t*)(ws + 5 * SZ + 8388608);             // 1 MB bias frags
  ushort_t* wqkvbf  = (ushort_t*)(ws + 5 * SZ + 8388608 + 1048576);
  ushort_t* wprojbf = (ushort_t*)(ws + 5 * SZ + 8388608 + 1048576 + 393216);

  cvt_tile_w<<<dim3(6144), dim3(256), 0, stream>>>(x, xbf, MROWS * 32);
  cvt_tile_w<<<dim3(96), dim3(256), 0, stream>>>(qkv_w, wqkvbf, 768 * 32);
  cvt_tile_w<<<dim3(32), dim3(256), 0, stream>>>(proj_w, wprojbf, 256 * 32);
  mask_prep<<<dim3(64, 8, 8), dim3(256), 0, stream>>>(mask, mfws);
  bias_prep<<<dim3(8, 8), dim3(256), 0, stream>>>(idx, table, bfws);
  qkv_gemm<<<dim3(2304), dim3(256), 0, stream>>>(xbf, wqkvbf, qkv_b, qws, kws, vtws);
  attn_kernel<<<dim3(1536), dim3(512), 0, stream>>>(qws, kws, vtws, mfws, bfws, aows);
  proj_gemm<<<dim3(768), dim3(256), 0, stream>>>(aows, wprojbf, proj_b, out);
}

// Round 8
// 242.110 us; speedup vs baseline: 1.1487x; 1.0327x over previous
//
#include <hip/hip_runtime.h>

typedef unsigned short ushort_t;
typedef __bf16 bf16x8 __attribute__((ext_vector_type(8)));
typedef float floatx4 __attribute__((ext_vector_type(4)));
typedef float floatx16 __attribute__((ext_vector_type(16)));

#define B_WIN 192
#define NTOK 256
#define CDIM 256
#define NHEAD 8
#define HDIM 32
#define NWIN 64
#define MROWS (B_WIN * NTOK)   // 49152
#define LOG2E 1.4426950408889634f

__device__ __forceinline__ float uasf(unsigned int u) {
  float f; __builtin_memcpy(&f, &u, 4); return f;
}
__device__ __forceinline__ ushort_t f2bf(float f) {
  unsigned int u; __builtin_memcpy(&u, &f, 4);
  u = (u + 0x7fffu + ((u >> 16) & 1u)) >> 16;
  return (ushort_t)u;
}
__device__ __forceinline__ bf16x8 ldg8(const ushort_t* p) {
  return *reinterpret_cast<const bf16x8*>(p);
}
__device__ __forceinline__ void async_copy16(const void* g, void* l) {
  __builtin_amdgcn_global_load_lds(
      (const __attribute__((address_space(1))) unsigned int*)g,
      (__attribute__((address_space(3))) unsigned int*)l, 16, 0, 0);
}
__device__ __forceinline__ float fexp2(float x) {
  return __builtin_amdgcn_exp2f(x);
}
// HW packed f32->bf16 (RTNE) -- T12/m214-verified pattern: asm cvt_pk feeding
// the permlane32_swap BUILTIN. (R2's failure is now attributed to asm v_exp_f32,
// which is gone; this round is the clean A/B on that attribution.)
__device__ __forceinline__ unsigned cvtpk(float a, float b) {
  unsigned r; asm("v_cvt_pk_bf16_f32 %0, %1, %2" : "=v"(r) : "v"(a), "v"(b)); return r;
}
__device__ __forceinline__ void plswap(unsigned& a, unsigned& b) {
  auto r = __builtin_amdgcn_permlane32_swap(a, b, false, false);
  a = r[0]; b = r[1];
}

// ---------------- kernel 0: fp32 -> bf16 MFMA-TILED (rows x 256 cols) -------
// dst(row,col) = ((row>>4)*8 + (col>>5))*512 + ((col>>3)&3)*128 + (row&15)*8 + (col&7)
__global__ __launch_bounds__(256) void cvt_tile_w(const float* __restrict__ src,
                                                  ushort_t* __restrict__ dst, int n) {
  int t = blockIdx.x * 256 + threadIdx.x;
  if (t >= n) return;                       // n = NROWS*32 threads, 8 col-elems each
  int row = t >> 5;
  int kk = (t & 31) * 8;
  const float4* s = reinterpret_cast<const float4*>(src + (size_t)row * 256 + kk);
  float4 v0 = s[0], v1 = s[1];
  union { ushort_t u[8]; uint4 v; } pk;
  pk.u[0] = f2bf(v0.x); pk.u[1] = f2bf(v0.y); pk.u[2] = f2bf(v0.z); pk.u[3] = f2bf(v0.w);
  pk.u[4] = f2bf(v1.x); pk.u[5] = f2bf(v1.y); pk.u[6] = f2bf(v1.z); pk.u[7] = f2bf(v1.w);
  size_t base = (size_t)(((row >> 4) * 8 + (kk >> 5)) * 512 + ((kk >> 3) & 3) * 128 + (row & 15) * 8);
  *reinterpret_cast<uint4*>(dst + base) = pk.v;
}

// ---------------- kernel 1a: mask -> 32x32 C/D-fragment order, *LOG2E -------
__global__ __launch_bounds__(256) void mask_prep(const float* __restrict__ mask,
                                                 ushort_t* __restrict__ mf) {
  const int win = blockIdx.x;      // 0..63
  const int qt = blockIdx.y;       // 0..7
  const int kb = blockIdx.z;       // 0..7
  const int l = threadIdx.x & 63;
  const int rg = threadIdx.x >> 6; // reg group 0..3
  const int tq = qt * 32 + (l & 31);
  const int hl = l >> 5;
  const int tk0 = kb * 32 + rg * 8 + hl * 4;
  const float4 mv = *reinterpret_cast<const float4*>(mask + (size_t)win * 65536 + tq * 256 + tk0);
  union { ushort_t u[4]; uint2 w; } pk;
  pk.u[0] = f2bf(mv.x * LOG2E); pk.u[1] = f2bf(mv.y * LOG2E);
  pk.u[2] = f2bf(mv.z * LOG2E); pk.u[3] = f2bf(mv.w * LOG2E);
  size_t base = ((size_t)((qt * 8 + kb) * 2 + (rg >> 1))) * 512 + l * 8 + (rg & 1) * 4;
  *reinterpret_cast<uint2*>(mf + ((size_t)win << 16) + base) = pk.w;
}

// ---------------- kernel 1b: rel-pos bias -> fragment order, *LOG2E ---------
__global__ __launch_bounds__(256) void bias_prep(const int* __restrict__ idx,
                                                 const float* __restrict__ table,
                                                 ushort_t* __restrict__ bf) {
  const int qt = blockIdx.x;       // 0..7
  const int kb = blockIdx.y;       // 0..7
  const int l = threadIdx.x & 63;
  const int rg = threadIdx.x >> 6;
  const int tq = qt * 32 + (l & 31);
  const int hl = l >> 5;
  const int tk0 = kb * 32 + rg * 8 + hl * 4;
  const int4 ids = *reinterpret_cast<const int4*>(idx + tq * 256 + tk0);
  const int idarr[4] = {ids.x, ids.y, ids.z, ids.w};
  float v[8][4];
  #pragma unroll
  for (int r2 = 0; r2 < 4; ++r2) {
    const float* tr = table + (size_t)idarr[r2] * 8;
    float4 t0 = *reinterpret_cast<const float4*>(tr);
    float4 t1 = *reinterpret_cast<const float4*>(tr + 4);
    v[0][r2] = t0.x * LOG2E; v[1][r2] = t0.y * LOG2E;
    v[2][r2] = t0.z * LOG2E; v[3][r2] = t0.w * LOG2E;
    v[4][r2] = t1.x * LOG2E; v[5][r2] = t1.y * LOG2E;
    v[6][r2] = t1.z * LOG2E; v[7][r2] = t1.w * LOG2E;
  }
  size_t base = ((size_t)((qt * 8 + kb) * 2 + (rg >> 1))) * 512 + l * 8 + (rg & 1) * 4;
  #pragma unroll
  for (int h = 0; h < 8; ++h) {
    union { ushort_t u[4]; uint2 w; } pk;
    pk.u[0] = f2bf(v[h][0]); pk.u[1] = f2bf(v[h][1]);
    pk.u[2] = f2bf(v[h][2]); pk.u[3] = f2bf(v[h][3]);
    *reinterpret_cast<uint2*>(bf + ((size_t)h << 16) + base) = pk.w;
  }
}

// ---------------- kernel 2: QKV GEMM, 2-phase global_load_lds pipeline ------
__global__ __launch_bounds__(256) void qkv_gemm(
    const ushort_t* __restrict__ x, const ushort_t* __restrict__ wt,
    const float* __restrict__ qkvb, ushort_t* __restrict__ qws,
    ushort_t* __restrict__ kws, ushort_t* __restrict__ vtws) {
  __shared__ __align__(16) char lds[32768];   // A dbuf [2][8192] | B dbuf at +16384
  const int lane = threadIdx.x & 63;
  const int wv = threadIdx.x >> 6;
  const int ln = lane & 15, qd = lane >> 4;
  const int b = blockIdx.x;                 // 0..2303
  const int xcd = b & 7, lb = b >> 3;       // lb 0..287
  const int rtile = xcd * 48 + (lb % 48);   // 0..383
  const int ctile = lb / 48;                // 0..5
  const int row0 = rtile * 128 + (wv >> 1) * 64;
  const int colw = ctile * 128 + (wv & 1) * 64;

  const char* ag = (const char*)x + (size_t)rtile * 65536;   // 8 row-chunks x 8 kt x 1KB
  const char* bg = (const char*)wt + (size_t)ctile * 65536;  // 8 col-chunks x 8 kt x 1KB

  floatx4 acc[4][4];
  #pragma unroll
  for (int rt = 0; rt < 4; ++rt)
    #pragma unroll
    for (int ct = 0; ct < 4; ++ct)
      acc[rt][ct] = floatx4{0.f, 0.f, 0.f, 0.f};

  #define STAGE(buf, kt)                                                          \
    {                                                                             \
      _Pragma("unroll")                                                           \
      for (int c2 = 0; c2 < 2; ++c2) {                                            \
        int c = wv * 2 + c2;                                                      \
        async_copy16(ag + (((size_t)c * 8 + (kt)) << 10) + lane * 16,             \
                     lds + (buf) * 8192 + c * 1024);                              \
        async_copy16(bg + (((size_t)c * 8 + (kt)) << 10) + lane * 16,             \
                     lds + 16384 + (buf) * 8192 + c * 1024);                      \
      }                                                                           \
    }

  STAGE(0, 0);
  __syncthreads();      // drains vmcnt(0): buf0 ready

  int cur = 0;
  #pragma unroll
  for (int kt = 0; kt < 8; ++kt) {
    if (kt < 7) STAGE(cur ^ 1, kt + 1);
    const char* ab = lds + cur * 8192 + ((wv >> 1) * 4) * 1024 + qd * 256 + ln * 16;
    const char* bb = lds + 16384 + cur * 8192 + ((wv & 1) * 4) * 1024 + qd * 256 + ln * 16;
    bf16x8 a[4], bq[4];
    #pragma unroll
    for (int t = 0; t < 4; ++t) {
      a[t] = *reinterpret_cast<const bf16x8*>(ab + t * 1024);
      bq[t] = *reinterpret_cast<const bf16x8*>(bb + t * 1024);
    }
    #pragma unroll
    for (int rt = 0; rt < 4; ++rt)
      #pragma unroll
      for (int ct = 0; ct < 4; ++ct)
        acc[rt][ct] = __builtin_amdgcn_mfma_f32_16x16x32_bf16(a[rt], bq[ct],
                                                              acc[rt][ct], 0, 0, 0);
    if (kt < 7) __syncthreads();   // next buffer staged + this buffer consumed
    cur ^= 1;
  }
  #undef STAGE

  const int s = colw >> 8;  // 0=q, 1=k, 2=v (uniform per wave)
  const float SCLQ = 0.17677669529663687f * LOG2E;  // 1/sqrt(32) * log2(e)
  #pragma unroll
  for (int ct = 0; ct < 4; ++ct) {
    int colg = colw + ct * 16 + ln;
    float bcol = qkvb[colg];
    int cs = colg & 255;
    int h = cs >> 5, d = cs & 31;
    int dslice = d >> 4, hh = (d >> 3) & 1, j = d & 7;
    #pragma unroll
    for (int rt = 0; rt < 4; ++rt) {
      int rbase = row0 + rt * 16 + qd * 4;
      int bwin = rbase >> 8, tok0 = rbase & 255;
      size_t slab = (size_t)(bwin * 8 + h) * 8192;
      if (s == 2) {
        int kt2 = tok0 >> 4, h2 = (tok0 >> 3) & 1, jj = tok0 & 7;
        union { ushort_t u[4]; uint2 v; } pk;
        #pragma unroll
        for (int i = 0; i < 4; ++i) pk.u[i] = f2bf(acc[rt][ct][i] + bcol);
        *reinterpret_cast<uint2*>(vtws + slab + kt2 * 512 + h2 * 256 + d * 8 + jj) = pk.v;
      } else {
        int blk = tok0 >> 5, c0 = tok0 & 31;
        size_t base = slab + (size_t)((blk * 2 + dslice) * 512 + hh * 256 + c0 * 8 + j);
        if (s == 0) {
          #pragma unroll
          for (int i = 0; i < 4; ++i)
            qws[base + i * 8] = f2bf((acc[rt][ct][i] + bcol) * SCLQ);
        } else {
          #pragma unroll
          for (int i = 0; i < 4; ++i)
            kws[base + i * 8] = f2bf(acc[rt][ct][i] + bcol);
        }
      }
    }
  }
}

// ---------------- kernel 3: windowed attention, 32x32 MFMA ------------------
// Block remap: b = win + 64*h + 512*batch (64,512 = 0 mod 8 XCDs) -> all 24
// blocks sharing a mask slab land on ONE XCD -> mask re-reads are L2 hits.
// P-pack via HW v_cvt_pk_bf16_f32 (8 ops vs 80 manual).
__global__ __launch_bounds__(512, 4) void attn_kernel(
    const ushort_t* __restrict__ qws, const ushort_t* __restrict__ kws,
    const ushort_t* __restrict__ vtws, const ushort_t* __restrict__ mf,
    const ushort_t* __restrict__ bfr, ushort_t* __restrict__ aows) {
  __shared__ __align__(16) ushort_t lds_kv[16384];   // K 16KB | V 16KB
  __shared__ float inv_lds[256];                     // 32 per wave
  const int lane = threadIdx.x & 63;
  const int wv = threadIdx.x >> 6;
  const int b = blockIdx.x;        // win + 64*h + 512*batch
  const int win = b & 63;
  const int h = (b >> 6) & 7;
  const int batch = b >> 9;
  const int bwin = batch * 64 + win;
  const int bh = bwin * 8 + h;

  {
    const char* kg = (const char*)(kws + (size_t)bh * 8192);
    const char* vg = (const char*)(vtws + (size_t)bh * 8192);
    #pragma unroll
    for (int r = 0; r < 2; ++r) {
      int off = r * 8192 + wv * 1024;
      async_copy16(kg + off + lane * 16, (char*)lds_kv + off);
      async_copy16(vg + off + lane * 16, (char*)lds_kv + 16384 + off);
    }
  }
  __syncthreads();

  const int qt = wv;            // 32-token q tile per wave
  const int hl = lane >> 5;
  const ushort_t* qb = qws + (size_t)bh * 8192 + qt * 1024 + lane * 8;
  const bf16x8 qf0 = ldg8(qb);          // dslice 0
  const bf16x8 qf1 = ldg8(qb + 512);    // dslice 1
  const ushort_t* mp = mf + ((size_t)win << 16) + qt * 8192 + lane * 8;
  const ushort_t* cp = bfr + ((size_t)h << 16) + qt * 8192 + lane * 8;

  floatx16 o;
  #pragma unroll
  for (int i = 0; i < 16; ++i) o[i] = 0.f;
  float ss0 = 0.f, ss1 = 0.f, ss2 = 0.f, ss3 = 0.f;

  #pragma unroll
  for (int kb = 0; kb < 8; ++kb) {
    const uint4 m0 = *reinterpret_cast<const uint4*>(mp + kb * 1024);
    const uint4 m1 = *reinterpret_cast<const uint4*>(mp + kb * 1024 + 512);
    const uint4 c0 = *reinterpret_cast<const uint4*>(cp + kb * 1024);
    const uint4 c1 = *reinterpret_cast<const uint4*>(cp + kb * 1024 + 512);
    floatx16 st;
    st[0]  = uasf(m0.x << 16) + uasf(c0.x << 16);
    st[1]  = uasf(m0.x & 0xffff0000u) + uasf(c0.x & 0xffff0000u);
    st[2]  = uasf(m0.y << 16) + uasf(c0.y << 16);
    st[3]  = uasf(m0.y & 0xffff0000u) + uasf(c0.y & 0xffff0000u);
    st[4]  = uasf(m0.z << 16) + uasf(c0.z << 16);
    st[5]  = uasf(m0.z & 0xffff0000u) + uasf(c0.z & 0xffff0000u);
    st[6]  = uasf(m0.w << 16) + uasf(c0.w << 16);
    st[7]  = uasf(m0.w & 0xffff0000u) + uasf(c0.w & 0xffff0000u);
    st[8]  = uasf(m1.x << 16) + uasf(c1.x << 16);
    st[9]  = uasf(m1.x & 0xffff0000u) + uasf(c1.x & 0xffff0000u);
    st[10] = uasf(m1.y << 16) + uasf(c1.y << 16);
    st[11] = uasf(m1.y & 0xffff0000u) + uasf(c1.y & 0xffff0000u);
    st[12] = uasf(m1.z << 16) + uasf(c1.z << 16);
    st[13] = uasf(m1.z & 0xffff0000u) + uasf(c1.z & 0xffff0000u);
    st[14] = uasf(m1.w << 16) + uasf(c1.w << 16);
    st[15] = uasf(m1.w & 0xffff0000u) + uasf(c1.w & 0xffff0000u);

    const bf16x8 kf0 = *reinterpret_cast<const bf16x8*>(&lds_kv[(kb * 2 + 0) * 512 + lane * 8]);
    const bf16x8 kf1 = *reinterpret_cast<const bf16x8*>(&lds_kv[(kb * 2 + 1) * 512 + lane * 8]);
    st = __builtin_amdgcn_mfma_f32_32x32x16_bf16(kf0, qf0, st, 0, 0, 0);
    st = __builtin_amdgcn_mfma_f32_32x32x16_bf16(kf1, qf1, st, 0, 0, 0);

    #pragma unroll
    for (int i = 0; i < 16; i += 4) {
      float e0 = fexp2(st[i]);     st[i]     = e0; ss0 += e0;
      float e1 = fexp2(st[i + 1]); st[i + 1] = e1; ss1 += e1;
      float e2 = fexp2(st[i + 2]); st[i + 2] = e2; ss2 += e2;
      float e3 = fexp2(st[i + 3]); st[i + 3] = e3; ss3 += e3;
    }

    // pack P->bf16 pairs via HW cvt_pk (RTNE); assemble PV A-frags via half-swap
    unsigned p0 = cvtpk(st[0], st[1]),   p1 = cvtpk(st[2], st[3]);
    unsigned p2 = cvtpk(st[4], st[5]),   p3 = cvtpk(st[6], st[7]);
    unsigned p4 = cvtpk(st[8], st[9]),   p5 = cvtpk(st[10], st[11]);
    unsigned p6 = cvtpk(st[12], st[13]), p7 = cvtpk(st[14], st[15]);
    plswap(p0, p2);
    plswap(p1, p3);
    plswap(p4, p6);
    plswap(p5, p7);
    union { unsigned u[4]; bf16x8 v; } afe, afo;
    afe.u[0] = p0; afe.u[1] = p1; afe.u[2] = p2; afe.u[3] = p3;
    afo.u[0] = p4; afo.u[1] = p5; afo.u[2] = p6; afo.u[3] = p7;

    const bf16x8 bv0 = *reinterpret_cast<const bf16x8*>(&lds_kv[8192 + (kb * 2 + 0) * 512 + lane * 8]);
    const bf16x8 bv1 = *reinterpret_cast<const bf16x8*>(&lds_kv[8192 + (kb * 2 + 1) * 512 + lane * 8]);
    o = __builtin_amdgcn_mfma_f32_32x32x16_bf16(afe.v, bv0, o, 0, 0, 0);
    o = __builtin_amdgcn_mfma_f32_32x32x16_bf16(afo.v, bv1, o, 0, 0, 0);
  }

  float ssum = (ss0 + ss1) + (ss2 + ss3);
  ssum += __shfl_xor(ssum, 32, 64);
  const float inv = 1.0f / ssum;
  inv_lds[wv * 32 + (lane & 31)] = inv;
  __builtin_amdgcn_s_waitcnt(0);
  const float4 iv0 = *reinterpret_cast<const float4*>(&inv_lds[wv * 32 + 0 + hl * 4]);
  const float4 iv1 = *reinterpret_cast<const float4*>(&inv_lds[wv * 32 + 8 + hl * 4]);
  const float4 iv2 = *reinterpret_cast<const float4*>(&inv_lds[wv * 32 + 16 + hl * 4]);
  const float4 iv3 = *reinterpret_cast<const float4*>(&inv_lds[wv * 32 + 24 + hl * 4]);

  // tiled-A scatter: halfword = ((bwin*16 + 2qt + (r>>1))*8 + h)*512
  //                  + ((d>>3)&3)*128 + (8*(r&1) + 4*hl + i)*8 + (d&7)
  const int d = lane & 31;
  ushort_t* op = aows + (((size_t)(bwin * 16 + 2 * qt) * 8 + h) << 9)
                 + ((d >> 3) & 3) * 128 + hl * 32 + (d & 7);
  op[0 * 8]              = f2bf(o[0]  * iv0.x);
  op[1 * 8]              = f2bf(o[1]  * iv0.y);
  op[2 * 8]              = f2bf(o[2]  * iv0.z);
  op[3 * 8]              = f2bf(o[3]  * iv0.w);
  op[64 + 0 * 8]         = f2bf(o[4]  * iv1.x);
  op[64 + 1 * 8]         = f2bf(o[5]  * iv1.y);
  op[64 + 2 * 8]         = f2bf(o[6]  * iv1.z);
  op[64 + 3 * 8]         = f2bf(o[7]  * iv1.w);
  op[4096 + 0 * 8]       = f2bf(o[8]  * iv2.x);
  op[4096 + 1 * 8]       = f2bf(o[9]  * iv2.y);
  op[4096 + 2 * 8]       = f2bf(o[10] * iv2.z);
  op[4096 + 3 * 8]       = f2bf(o[11] * iv2.w);
  op[4096 + 64 + 0 * 8]  = f2bf(o[12] * iv3.x);
  op[4096 + 64 + 1 * 8]  = f2bf(o[13] * iv3.y);
  op[4096 + 64 + 2 * 8]  = f2bf(o[14] * iv3.z);
  op[4096 + 64 + 3 * 8]  = f2bf(o[15] * iv3.w);
}

// ---------------- kernel 4: output projection, 2-phase LDS pipeline ---------
__global__ __launch_bounds__(256) void proj_gemm(
    const ushort_t* __restrict__ a_, const ushort_t* __restrict__ wt,
    const float* __restrict__ pb, float* __restrict__ out) {
  __shared__ __align__(16) char lds[32768];
  const int lane = threadIdx.x & 63;
  const int wv = threadIdx.x >> 6;
  const int ln = lane & 15, qd = lane >> 4;
  const int b = blockIdx.x;                 // 0..767
  const int xcd = b & 7, lb = b >> 3;       // lb 0..95
  const int rtile = xcd * 48 + (lb % 48);   // 0..383
  const int ctile = lb / 48;                // 0..1
  const int row0 = rtile * 128 + (wv >> 1) * 64;
  const int colw = ctile * 128 + (wv & 1) * 64;

  const char* ag = (const char*)a_ + (size_t)rtile * 65536;
  const char* bg = (const char*)wt + (size_t)ctile * 65536;

  floatx4 acc[4][4];
  #pragma unroll
  for (int rt = 0; rt < 4; ++rt)
    #pragma unroll
    for (int ct = 0; ct < 4; ++ct)
      acc[rt][ct] = floatx4{0.f, 0.f, 0.f, 0.f};

  #define STAGE(buf, kt)                                                          \
    {                                                                             \
      _Pragma("unroll")                                                           \
      for (int c2 = 0; c2 < 2; ++c2) {                                            \
        int c = wv * 2 + c2;                                                      \
        async_copy16(ag + (((size_t)c * 8 + (kt)) << 10) + lane * 16,             \
                     lds + (buf) * 8192 + c * 1024);                              \
        async_copy16(bg + (((size_t)c * 8 + (kt)) << 10) + lane * 16,             \
                     lds + 16384 + (buf) * 8192 + c * 1024);                      \
      }                                                                           \
    }

  STAGE(0, 0);
  __syncthreads();

  int cur = 0;
  #pragma unroll
  for (int kt = 0; kt < 8; ++kt) {
    if (kt < 7) STAGE(cur ^ 1, kt + 1);
    const char* ab = lds + cur * 8192 + ((wv >> 1) * 4) * 1024 + qd * 256 + ln * 16;
    const char* bb = lds + 16384 + cur * 8192 + ((wv & 1) * 4) * 1024 + qd * 256 + ln * 16;
    bf16x8 a[4], bq[4];
    #pragma unroll
    for (int t = 0; t < 4; ++t) {
      a[t] = *reinterpret_cast<const bf16x8*>(ab + t * 1024);
      bq[t] = *reinterpret_cast<const bf16x8*>(bb + t * 1024);
    }
    #pragma unroll
    for (int rt = 0; rt < 4; ++rt)
      #pragma unroll
      for (int ct = 0; ct < 4; ++ct)
        acc[rt][ct] = __builtin_amdgcn_mfma_f32_16x16x32_bf16(a[rt], bq[ct],
                                                              acc[rt][ct], 0, 0, 0);
    if (kt < 7) __syncthreads();
    cur ^= 1;
  }
  #undef STAGE

  #pragma unroll
  for (int ct = 0; ct < 4; ++ct) {
    int colg = colw + ct * 16 + ln;
    float bcol = pb[colg];
    #pragma unroll
    for (int rt = 0; rt < 4; ++rt) {
      int rbase = row0 + rt * 16 + qd * 4;
      #pragma unroll
      for (int i = 0; i < 4; ++i)
        out[(size_t)(rbase + i) * 256 + colg] = acc[rt][ct][i] + bcol;
    }
  }
}

// ---------------- launch ----------------------------------------------------
extern "C" void kernel_launch(void* const* d_in, const int* in_sizes, int n_in,
                              void* d_out, int out_size, void* d_ws, size_t ws_size,
                              hipStream_t stream) {
  const float* x      = (const float*)d_in[0];
  const float* mask   = (const float*)d_in[1];
  const float* qkv_w  = (const float*)d_in[2];
  const float* qkv_b  = (const float*)d_in[3];
  const float* proj_w = (const float*)d_in[4];
  const float* proj_b = (const float*)d_in[5];
  const float* table  = (const float*)d_in[6];
  const int*   idx    = (const int*)d_in[7];
  float* out = (float*)d_out;

  char* ws = (char*)d_ws;
  const size_t SZ = (size_t)MROWS * CDIM * 2;  // 25165824 B per bf16 buffer
  ushort_t* xbf  = (ushort_t*)(ws);            // tiled-A x
  ushort_t* qws  = (ushort_t*)(ws + SZ);       // q fragment slabs
  ushort_t* kws  = (ushort_t*)(ws + 2 * SZ);   // k fragment slabs
  ushort_t* vtws = (ushort_t*)(ws + 3 * SZ);   // v fragment slabs
  ushort_t* aows = (ushort_t*)(ws + 4 * SZ);   // tiled-A attn output
  ushort_t* mfws = (ushort_t*)(ws + 5 * SZ);                       // 8.4 MB mask frags
  ushort_t* bfws = (ushort_t*)(ws + 5 * SZ + 8388608);             // 1 MB bias frags
  ushort_t* wqkvbf  = (ushort_t*)(ws + 5 * SZ + 8388608 + 1048576);
  ushort_t* wprojbf = (ushort_t*)(ws + 5 * SZ + 8388608 + 1048576 + 393216);

  cvt_tile_w<<<dim3(6144), dim3(256), 0, stream>>>(x, xbf, MROWS * 32);
  cvt_tile_w<<<dim3(96), dim3(256), 0, stream>>>(qkv_w, wqkvbf, 768 * 32);
  cvt_tile_w<<<dim3(32), dim3(256), 0, stream>>>(proj_w, wprojbf, 256 * 32);
  mask_prep<<<dim3(64, 8, 8), dim3(256), 0, stream>>>(mask, mfws);
  bias_prep<<<dim3(8, 8), dim3(256), 0, stream>>>(idx, table, bfws);
  qkv_gemm<<<dim3(2304), dim3(256), 0, stream>>>(xbf, wqkvbf, qkv_b, qws, kws, vtws);
  attn_kernel<<<dim3(1536), dim3(512), 0, stream>>>(qws, kws, vtws, mfws, bfws, aows);
  proj_gemm<<<dim3(768), dim3(256), 0, stream>>>(aows, wprojbf, proj_b, out);
}

// Round 9
// 236.081 us; speedup vs baseline: 1.1781x; 1.0255x over previous
//
#include <hip/hip_runtime.h>

typedef unsigned short ushort_t;
typedef __bf16 bf16x8 __attribute__((ext_vector_type(8)));
typedef float floatx4 __attribute__((ext_vector_type(4)));
typedef float floatx16 __attribute__((ext_vector_type(16)));

#define B_WIN 192
#define NTOK 256
#define CDIM 256
#define NHEAD 8
#define HDIM 32
#define NWIN 64
#define MROWS (B_WIN * NTOK)   // 49152
#define LOG2E 1.4426950408889634f

__device__ __forceinline__ float uasf(unsigned int u) {
  float f; __builtin_memcpy(&f, &u, 4); return f;
}
__device__ __forceinline__ ushort_t f2bf(float f) {
  unsigned int u; __builtin_memcpy(&u, &f, 4);
  u = (u + 0x7fffu + ((u >> 16) & 1u)) >> 16;
  return (ushort_t)u;
}
__device__ __forceinline__ bf16x8 ldg8(const ushort_t* p) {
  return *reinterpret_cast<const bf16x8*>(p);
}
__device__ __forceinline__ void async_copy16(const void* g, void* l) {
  __builtin_amdgcn_global_load_lds(
      (const __attribute__((address_space(1))) unsigned int*)g,
      (__attribute__((address_space(3))) unsigned int*)l, 16, 0, 0);
}
__device__ __forceinline__ float fexp2(float x) {
  return __builtin_amdgcn_exp2f(x);
}
// HW packed f32->bf16 (RTNE) -- T12/m214-verified (R8 A/B: absmax unchanged)
__device__ __forceinline__ unsigned cvtpk(float a, float b) {
  unsigned r; asm("v_cvt_pk_bf16_f32 %0, %1, %2" : "=v"(r) : "v"(a), "v"(b)); return r;
}
__device__ __forceinline__ void plswap(unsigned& a, unsigned& b) {
  auto r = __builtin_amdgcn_permlane32_swap(a, b, false, false);
  a = r[0]; b = r[1];
}

// ---------------- kernel 0: fp32 -> bf16 MFMA-TILED (rows x 256 cols) -------
// dst(row,col) = ((row>>4)*8 + (col>>5))*512 + ((col>>3)&3)*128 + (row&15)*8 + (col&7)
__global__ __launch_bounds__(256) void cvt_tile_w(const float* __restrict__ src,
                                                  ushort_t* __restrict__ dst, int n) {
  int t = blockIdx.x * 256 + threadIdx.x;
  if (t >= n) return;                       // n = NROWS*32 threads, 8 col-elems each
  int row = t >> 5;
  int kk = (t & 31) * 8;
  const float4* s = reinterpret_cast<const float4*>(src + (size_t)row * 256 + kk);
  float4 v0 = s[0], v1 = s[1];
  union { ushort_t u[8]; uint4 v; } pk;
  pk.u[0] = f2bf(v0.x); pk.u[1] = f2bf(v0.y); pk.u[2] = f2bf(v0.z); pk.u[3] = f2bf(v0.w);
  pk.u[4] = f2bf(v1.x); pk.u[5] = f2bf(v1.y); pk.u[6] = f2bf(v1.z); pk.u[7] = f2bf(v1.w);
  size_t base = (size_t)(((row >> 4) * 8 + (kk >> 5)) * 512 + ((kk >> 3) & 3) * 128 + (row & 15) * 8);
  *reinterpret_cast<uint4*>(dst + base) = pk.v;
}

// ---------------- kernel 1a: mask -> 32x32 C/D-fragment order, *LOG2E -------
__global__ __launch_bounds__(256) void mask_prep(const float* __restrict__ mask,
                                                 ushort_t* __restrict__ mf) {
  const int win = blockIdx.x;      // 0..63
  const int qt = blockIdx.y;       // 0..7
  const int kb = blockIdx.z;       // 0..7
  const int l = threadIdx.x & 63;
  const int rg = threadIdx.x >> 6; // reg group 0..3
  const int tq = qt * 32 + (l & 31);
  const int hl = l >> 5;
  const int tk0 = kb * 32 + rg * 8 + hl * 4;
  const float4 mv = *reinterpret_cast<const float4*>(mask + (size_t)win * 65536 + tq * 256 + tk0);
  union { ushort_t u[4]; uint2 w; } pk;
  pk.u[0] = f2bf(mv.x * LOG2E); pk.u[1] = f2bf(mv.y * LOG2E);
  pk.u[2] = f2bf(mv.z * LOG2E); pk.u[3] = f2bf(mv.w * LOG2E);
  size_t base = ((size_t)((qt * 8 + kb) * 2 + (rg >> 1))) * 512 + l * 8 + (rg & 1) * 4;
  *reinterpret_cast<uint2*>(mf + ((size_t)win << 16) + base) = pk.w;
}

// ---------------- kernel 1b: rel-pos bias -> fragment order, *LOG2E ---------
__global__ __launch_bounds__(256) void bias_prep(const int* __restrict__ idx,
                                                 const float* __restrict__ table,
                                                 ushort_t* __restrict__ bf) {
  const int qt = blockIdx.x;       // 0..7
  const int kb = blockIdx.y;       // 0..7
  const int l = threadIdx.x & 63;
  const int rg = threadIdx.x >> 6;
  const int tq = qt * 32 + (l & 31);
  const int hl = l >> 5;
  const int tk0 = kb * 32 + rg * 8 + hl * 4;
  const int4 ids = *reinterpret_cast<const int4*>(idx + tq * 256 + tk0);
  const int idarr[4] = {ids.x, ids.y, ids.z, ids.w};
  float v[8][4];
  #pragma unroll
  for (int r2 = 0; r2 < 4; ++r2) {
    const float* tr = table + (size_t)idarr[r2] * 8;
    float4 t0 = *reinterpret_cast<const float4*>(tr);
    float4 t1 = *reinterpret_cast<const float4*>(tr + 4);
    v[0][r2] = t0.x * LOG2E; v[1][r2] = t0.y * LOG2E;
    v[2][r2] = t0.z * LOG2E; v[3][r2] = t0.w * LOG2E;
    v[4][r2] = t1.x * LOG2E; v[5][r2] = t1.y * LOG2E;
    v[6][r2] = t1.z * LOG2E; v[7][r2] = t1.w * LOG2E;
  }
  size_t base = ((size_t)((qt * 8 + kb) * 2 + (rg >> 1))) * 512 + l * 8 + (rg & 1) * 4;
  #pragma unroll
  for (int h = 0; h < 8; ++h) {
    union { ushort_t u[4]; uint2 w; } pk;
    pk.u[0] = f2bf(v[h][0]); pk.u[1] = f2bf(v[h][1]);
    pk.u[2] = f2bf(v[h][2]); pk.u[3] = f2bf(v[h][3]);
    *reinterpret_cast<uint2*>(bf + ((size_t)h << 16) + base) = pk.w;
  }
}

// ---------------- kernel 2: QKV GEMM, 3-buf counted-vmcnt pipeline (T3+T4) --
// Per K-step: {vmcnt(4) -> s_barrier -> STAGE((kt+2)%3) -> ds_read+MFMA}.
// Counted wait keeps next tile's 4 loads in flight ACROSS the barrier (never
// drain to 0 in-loop). buf[(kt+2)%3] was last read at kt-1 and all waves have
// passed barrier(kt) -> overwrite is race-free with a single barrier/step.
__global__ __launch_bounds__(256) void qkv_gemm(
    const ushort_t* __restrict__ x, const ushort_t* __restrict__ wt,
    const float* __restrict__ qkvb, ushort_t* __restrict__ qws,
    ushort_t* __restrict__ kws, ushort_t* __restrict__ vtws) {
  __shared__ __align__(16) char lds[49152];   // A bufs [3][8192] | B bufs at +24576
  const int lane = threadIdx.x & 63;
  const int wv = threadIdx.x >> 6;
  const int ln = lane & 15, qd = lane >> 4;
  const int b = blockIdx.x;                 // 0..2303
  const int xcd = b & 7, lb = b >> 3;       // lb 0..287
  const int rtile = xcd * 48 + (lb % 48);   // 0..383
  const int ctile = lb / 48;                // 0..5
  const int row0 = rtile * 128 + (wv >> 1) * 64;
  const int colw = ctile * 128 + (wv & 1) * 64;

  const char* ag = (const char*)x + (size_t)rtile * 65536;   // 8 row-chunks x 8 kt x 1KB
  const char* bg = (const char*)wt + (size_t)ctile * 65536;  // 8 col-chunks x 8 kt x 1KB

  floatx4 acc[4][4];
  #pragma unroll
  for (int rt = 0; rt < 4; ++rt)
    #pragma unroll
    for (int ct = 0; ct < 4; ++ct)
      acc[rt][ct] = floatx4{0.f, 0.f, 0.f, 0.f};

  // wave wv stages chunks {2wv, 2wv+1} of A and B: 4 global_load_lds per wave
  #define STAGE(buf, kt)                                                          \
    {                                                                             \
      _Pragma("unroll")                                                           \
      for (int c2 = 0; c2 < 2; ++c2) {                                            \
        int c = wv * 2 + c2;                                                      \
        async_copy16(ag + (((size_t)c * 8 + (kt)) << 10) + lane * 16,             \
                     lds + (buf) * 8192 + c * 1024);                              \
        async_copy16(bg + (((size_t)c * 8 + (kt)) << 10) + lane * 16,             \
                     lds + 24576 + (buf) * 8192 + c * 1024);                      \
      }                                                                           \
    }

  STAGE(0, 0);
  STAGE(1, 1);        // 8 loads in flight per wave

  #pragma unroll
  for (int kt = 0; kt < 8; ++kt) {
    if (kt < 7) asm volatile("s_waitcnt vmcnt(4)" ::: "memory");
    else        asm volatile("s_waitcnt vmcnt(0)" ::: "memory");
    __builtin_amdgcn_s_barrier();
    __builtin_amdgcn_sched_barrier(0);
    if (kt < 6) STAGE((kt + 2) % 3, kt + 2);
    const int cur = kt % 3;
    const char* ab = lds + cur * 8192 + ((wv >> 1) * 4) * 1024 + qd * 256 + ln * 16;
    const char* bb = lds + 24576 + cur * 8192 + ((wv & 1) * 4) * 1024 + qd * 256 + ln * 16;
    bf16x8 a[4], bq[4];
    #pragma unroll
    for (int t = 0; t < 4; ++t) {
      a[t] = *reinterpret_cast<const bf16x8*>(ab + t * 1024);
      bq[t] = *reinterpret_cast<const bf16x8*>(bb + t * 1024);
    }
    #pragma unroll
    for (int rt = 0; rt < 4; ++rt)
      #pragma unroll
      for (int ct = 0; ct < 4; ++ct)
        acc[rt][ct] = __builtin_amdgcn_mfma_f32_16x16x32_bf16(a[rt], bq[ct],
                                                              acc[rt][ct], 0, 0, 0);
  }
  #undef STAGE

  const int s = colw >> 8;  // 0=q, 1=k, 2=v (uniform per wave)
  const float SCLQ = 0.17677669529663687f * LOG2E;  // 1/sqrt(32) * log2(e)
  #pragma unroll
  for (int ct = 0; ct < 4; ++ct) {
    int colg = colw + ct * 16 + ln;
    float bcol = qkvb[colg];
    int cs = colg & 255;
    int h = cs >> 5, d = cs & 31;
    int dslice = d >> 4, hh = (d >> 3) & 1, j = d & 7;
    #pragma unroll
    for (int rt = 0; rt < 4; ++rt) {
      int rbase = row0 + rt * 16 + qd * 4;
      int bwin = rbase >> 8, tok0 = rbase & 255;
      size_t slab = (size_t)(bwin * 8 + h) * 8192;
      if (s == 2) {
        int kt2 = tok0 >> 4, h2 = (tok0 >> 3) & 1, jj = tok0 & 7;
        union { ushort_t u[4]; uint2 v; } pk;
        #pragma unroll
        for (int i = 0; i < 4; ++i) pk.u[i] = f2bf(acc[rt][ct][i] + bcol);
        *reinterpret_cast<uint2*>(vtws + slab + kt2 * 512 + h2 * 256 + d * 8 + jj) = pk.v;
      } else {
        int blk = tok0 >> 5, c0 = tok0 & 31;
        size_t base = slab + (size_t)((blk * 2 + dslice) * 512 + hh * 256 + c0 * 8 + j);
        if (s == 0) {
          #pragma unroll
          for (int i = 0; i < 4; ++i)
            qws[base + i * 8] = f2bf((acc[rt][ct][i] + bcol) * SCLQ);
        } else {
          #pragma unroll
          for (int i = 0; i < 4; ++i)
            kws[base + i * 8] = f2bf(acc[rt][ct][i] + bcol);
        }
      }
    }
  }
}

// ---------------- kernel 3: windowed attention, 32x32 MFMA ------------------
__global__ __launch_bounds__(512, 4) void attn_kernel(
    const ushort_t* __restrict__ qws, const ushort_t* __restrict__ kws,
    const ushort_t* __restrict__ vtws, const ushort_t* __restrict__ mf,
    const ushort_t* __restrict__ bfr, ushort_t* __restrict__ aows) {
  __shared__ __align__(16) ushort_t lds_kv[16384];   // K 16KB | V 16KB
  __shared__ float inv_lds[256];                     // 32 per wave
  const int lane = threadIdx.x & 63;
  const int wv = threadIdx.x >> 6;
  const int b = blockIdx.x;        // win + 64*h + 512*batch
  const int win = b & 63;
  const int h = (b >> 6) & 7;
  const int batch = b >> 9;
  const int bwin = batch * 64 + win;
  const int bh = bwin * 8 + h;

  {
    const char* kg = (const char*)(kws + (size_t)bh * 8192);
    const char* vg = (const char*)(vtws + (size_t)bh * 8192);
    #pragma unroll
    for (int r = 0; r < 2; ++r) {
      int off = r * 8192 + wv * 1024;
      async_copy16(kg + off + lane * 16, (char*)lds_kv + off);
      async_copy16(vg + off + lane * 16, (char*)lds_kv + 16384 + off);
    }
  }
  __syncthreads();

  const int qt = wv;            // 32-token q tile per wave
  const int hl = lane >> 5;
  const ushort_t* qb = qws + (size_t)bh * 8192 + qt * 1024 + lane * 8;
  const bf16x8 qf0 = ldg8(qb);          // dslice 0
  const bf16x8 qf1 = ldg8(qb + 512);    // dslice 1
  const ushort_t* mp = mf + ((size_t)win << 16) + qt * 8192 + lane * 8;
  const ushort_t* cp = bfr + ((size_t)h << 16) + qt * 8192 + lane * 8;

  floatx16 o;
  #pragma unroll
  for (int i = 0; i < 16; ++i) o[i] = 0.f;
  float ss0 = 0.f, ss1 = 0.f, ss2 = 0.f, ss3 = 0.f;

  #pragma unroll
  for (int kb = 0; kb < 8; ++kb) {
    const uint4 m0 = *reinterpret_cast<const uint4*>(mp + kb * 1024);
    const uint4 m1 = *reinterpret_cast<const uint4*>(mp + kb * 1024 + 512);
    const uint4 c0 = *reinterpret_cast<const uint4*>(cp + kb * 1024);
    const uint4 c1 = *reinterpret_cast<const uint4*>(cp + kb * 1024 + 512);
    floatx16 st;
    st[0]  = uasf(m0.x << 16) + uasf(c0.x << 16);
    st[1]  = uasf(m0.x & 0xffff0000u) + uasf(c0.x & 0xffff0000u);
    st[2]  = uasf(m0.y << 16) + uasf(c0.y << 16);
    st[3]  = uasf(m0.y & 0xffff0000u) + uasf(c0.y & 0xffff0000u);
    st[4]  = uasf(m0.z << 16) + uasf(c0.z << 16);
    st[5]  = uasf(m0.z & 0xffff0000u) + uasf(c0.z & 0xffff0000u);
    st[6]  = uasf(m0.w << 16) + uasf(c0.w << 16);
    st[7]  = uasf(m0.w & 0xffff0000u) + uasf(c0.w & 0xffff0000u);
    st[8]  = uasf(m1.x << 16) + uasf(c1.x << 16);
    st[9]  = uasf(m1.x & 0xffff0000u) + uasf(c1.x & 0xffff0000u);
    st[10] = uasf(m1.y << 16) + uasf(c1.y << 16);
    st[11] = uasf(m1.y & 0xffff0000u) + uasf(c1.y & 0xffff0000u);
    st[12] = uasf(m1.z << 16) + uasf(c1.z << 16);
    st[13] = uasf(m1.z & 0xffff0000u) + uasf(c1.z & 0xffff0000u);
    st[14] = uasf(m1.w << 16) + uasf(c1.w << 16);
    st[15] = uasf(m1.w & 0xffff0000u) + uasf(c1.w & 0xffff0000u);

    const bf16x8 kf0 = *reinterpret_cast<const bf16x8*>(&lds_kv[(kb * 2 + 0) * 512 + lane * 8]);
    const bf16x8 kf1 = *reinterpret_cast<const bf16x8*>(&lds_kv[(kb * 2 + 1) * 512 + lane * 8]);
    st = __builtin_amdgcn_mfma_f32_32x32x16_bf16(kf0, qf0, st, 0, 0, 0);
    st = __builtin_amdgcn_mfma_f32_32x32x16_bf16(kf1, qf1, st, 0, 0, 0);

    #pragma unroll
    for (int i = 0; i < 16; i += 4) {
      float e0 = fexp2(st[i]);     st[i]     = e0; ss0 += e0;
      float e1 = fexp2(st[i + 1]); st[i + 1] = e1; ss1 += e1;
      float e2 = fexp2(st[i + 2]); st[i + 2] = e2; ss2 += e2;
      float e3 = fexp2(st[i + 3]); st[i + 3] = e3; ss3 += e3;
    }

    unsigned p0 = cvtpk(st[0], st[1]),   p1 = cvtpk(st[2], st[3]);
    unsigned p2 = cvtpk(st[4], st[5]),   p3 = cvtpk(st[6], st[7]);
    unsigned p4 = cvtpk(st[8], st[9]),   p5 = cvtpk(st[10], st[11]);
    unsigned p6 = cvtpk(st[12], st[13]), p7 = cvtpk(st[14], st[15]);
    plswap(p0, p2);
    plswap(p1, p3);
    plswap(p4, p6);
    plswap(p5, p7);
    union { unsigned u[4]; bf16x8 v; } afe, afo;
    afe.u[0] = p0; afe.u[1] = p1; afe.u[2] = p2; afe.u[3] = p3;
    afo.u[0] = p4; afo.u[1] = p5; afo.u[2] = p6; afo.u[3] = p7;

    const bf16x8 bv0 = *reinterpret_cast<const bf16x8*>(&lds_kv[8192 + (kb * 2 + 0) * 512 + lane * 8]);
    const bf16x8 bv1 = *reinterpret_cast<const bf16x8*>(&lds_kv[8192 + (kb * 2 + 1) * 512 + lane * 8]);
    o = __builtin_amdgcn_mfma_f32_32x32x16_bf16(afe.v, bv0, o, 0, 0, 0);
    o = __builtin_amdgcn_mfma_f32_32x32x16_bf16(afo.v, bv1, o, 0, 0, 0);
  }

  float ssum = (ss0 + ss1) + (ss2 + ss3);
  ssum += __shfl_xor(ssum, 32, 64);
  const float inv = 1.0f / ssum;
  inv_lds[wv * 32 + (lane & 31)] = inv;
  __builtin_amdgcn_s_waitcnt(0);
  const float4 iv0 = *reinterpret_cast<const float4*>(&inv_lds[wv * 32 + 0 + hl * 4]);
  const float4 iv1 = *reinterpret_cast<const float4*>(&inv_lds[wv * 32 + 8 + hl * 4]);
  const float4 iv2 = *reinterpret_cast<const float4*>(&inv_lds[wv * 32 + 16 + hl * 4]);
  const float4 iv3 = *reinterpret_cast<const float4*>(&inv_lds[wv * 32 + 24 + hl * 4]);

  // tiled-A scatter
  const int d = lane & 31;
  ushort_t* op = aows + (((size_t)(bwin * 16 + 2 * qt) * 8 + h) << 9)
                 + ((d >> 3) & 3) * 128 + hl * 32 + (d & 7);
  op[0 * 8]              = f2bf(o[0]  * iv0.x);
  op[1 * 8]              = f2bf(o[1]  * iv0.y);
  op[2 * 8]              = f2bf(o[2]  * iv0.z);
  op[3 * 8]              = f2bf(o[3]  * iv0.w);
  op[64 + 0 * 8]         = f2bf(o[4]  * iv1.x);
  op[64 + 1 * 8]         = f2bf(o[5]  * iv1.y);
  op[64 + 2 * 8]         = f2bf(o[6]  * iv1.z);
  op[64 + 3 * 8]         = f2bf(o[7]  * iv1.w);
  op[4096 + 0 * 8]       = f2bf(o[8]  * iv2.x);
  op[4096 + 1 * 8]       = f2bf(o[9]  * iv2.y);
  op[4096 + 2 * 8]       = f2bf(o[10] * iv2.z);
  op[4096 + 3 * 8]       = f2bf(o[11] * iv2.w);
  op[4096 + 64 + 0 * 8]  = f2bf(o[12] * iv3.x);
  op[4096 + 64 + 1 * 8]  = f2bf(o[13] * iv3.y);
  op[4096 + 64 + 2 * 8]  = f2bf(o[14] * iv3.z);
  op[4096 + 64 + 3 * 8]  = f2bf(o[15] * iv3.w);
}

// ---------------- kernel 4: output projection, 3-buf counted-vmcnt ----------
__global__ __launch_bounds__(256) void proj_gemm(
    const ushort_t* __restrict__ a_, const ushort_t* __restrict__ wt,
    const float* __restrict__ pb, float* __restrict__ out) {
  __shared__ __align__(16) char lds[49152];
  const int lane = threadIdx.x & 63;
  const int wv = threadIdx.x >> 6;
  const int ln = lane & 15, qd = lane >> 4;
  const int b = blockIdx.x;                 // 0..767
  const int xcd = b & 7, lb = b >> 3;       // lb 0..95
  const int rtile = xcd * 48 + (lb % 48);   // 0..383
  const int ctile = lb / 48;                // 0..1
  const int row0 = rtile * 128 + (wv >> 1) * 64;
  const int colw = ctile * 128 + (wv & 1) * 64;

  const char* ag = (const char*)a_ + (size_t)rtile * 65536;
  const char* bg = (const char*)wt + (size_t)ctile * 65536;

  floatx4 acc[4][4];
  #pragma unroll
  for (int rt = 0; rt < 4; ++rt)
    #pragma unroll
    for (int ct = 0; ct < 4; ++ct)
      acc[rt][ct] = floatx4{0.f, 0.f, 0.f, 0.f};

  #define STAGE(buf, kt)                                                          \
    {                                                                             \
      _Pragma("unroll")                                                           \
      for (int c2 = 0; c2 < 2; ++c2) {                                            \
        int c = wv * 2 + c2;                                                      \
        async_copy16(ag + (((size_t)c * 8 + (kt)) << 10) + lane * 16,             \
                     lds + (buf) * 8192 + c * 1024);                              \
        async_copy16(bg + (((size_t)c * 8 + (kt)) << 10) + lane * 16,             \
                     lds + 24576 + (buf) * 8192 + c * 1024);                      \
      }                                                                           \
    }

  STAGE(0, 0);
  STAGE(1, 1);

  #pragma unroll
  for (int kt = 0; kt < 8; ++kt) {
    if (kt < 7) asm volatile("s_waitcnt vmcnt(4)" ::: "memory");
    else        asm volatile("s_waitcnt vmcnt(0)" ::: "memory");
    __builtin_amdgcn_s_barrier();
    __builtin_amdgcn_sched_barrier(0);
    if (kt < 6) STAGE((kt + 2) % 3, kt + 2);
    const int cur = kt % 3;
    const char* ab = lds + cur * 8192 + ((wv >> 1) * 4) * 1024 + qd * 256 + ln * 16;
    const char* bb = lds + 24576 + cur * 8192 + ((wv & 1) * 4) * 1024 + qd * 256 + ln * 16;
    bf16x8 a[4], bq[4];
    #pragma unroll
    for (int t = 0; t < 4; ++t) {
      a[t] = *reinterpret_cast<const bf16x8*>(ab + t * 1024);
      bq[t] = *reinterpret_cast<const bf16x8*>(bb + t * 1024);
    }
    #pragma unroll
    for (int rt = 0; rt < 4; ++rt)
      #pragma unroll
      for (int ct = 0; ct < 4; ++ct)
        acc[rt][ct] = __builtin_amdgcn_mfma_f32_16x16x32_bf16(a[rt], bq[ct],
                                                              acc[rt][ct], 0, 0, 0);
  }
  #undef STAGE

  #pragma unroll
  for (int ct = 0; ct < 4; ++ct) {
    int colg = colw + ct * 16 + ln;
    float bcol = pb[colg];
    #pragma unroll
    for (int rt = 0; rt < 4; ++rt) {
      int rbase = row0 + rt * 16 + qd * 4;
      #pragma unroll
      for (int i = 0; i < 4; ++i)
        out[(size_t)(rbase + i) * 256 + colg] = acc[rt][ct][i] + bcol;
    }
  }
}

// ---------------- launch ----------------------------------------------------
extern "C" void kernel_launch(void* const* d_in, const int* in_sizes, int n_in,
                              void* d_out, int out_size, void* d_ws, size_t ws_size,
                              hipStream_t stream) {
  const float* x      = (const float*)d_in[0];
  const float* mask   = (const float*)d_in[1];
  const float* qkv_w  = (const float*)d_in[2];
  const float* qkv_b  = (const float*)d_in[3];
  const float* proj_w = (const float*)d_in[4];
  const float* proj_b = (const float*)d_in[5];
  const float* table  = (const float*)d_in[6];
  const int*   idx    = (const int*)d_in[7];
  float* out = (float*)d_out;

  char* ws = (char*)d_ws;
  const size_t SZ = (size_t)MROWS * CDIM * 2;  // 25165824 B per bf16 buffer
  ushort_t* xbf  = (ushort_t*)(ws);            // tiled-A x
  ushort_t* qws  = (ushort_t*)(ws + SZ);       // q fragment slabs
  ushort_t* kws  = (ushort_t*)(ws + 2 * SZ);   // k fragment slabs
  ushort_t* vtws = (ushort_t*)(ws + 3 * SZ);   // v fragment slabs
  ushort_t* aows = (ushort_t*)(ws + 4 * SZ);   // tiled-A attn output
  ushort_t* mfws = (ushort_t*)(ws + 5 * SZ);                       // 8.4 MB mask frags
  ushort_t* bfws = (ushort_t*)(ws + 5 * SZ + 8388608);             // 1 MB bias frags
  ushort_t* wqkvbf  = (ushort_t*)(ws + 5 * SZ + 8388608 + 1048576);
  ushort_t* wprojbf = (ushort_t*)(ws + 5 * SZ + 8388608 + 1048576 + 393216);

  cvt_tile_w<<<dim3(6144), dim3(256), 0, stream>>>(x, xbf, MROWS * 32);
  cvt_tile_w<<<dim3(96), dim3(256), 0, stream>>>(qkv_w, wqkvbf, 768 * 32);
  cvt_tile_w<<<dim3(32), dim3(256), 0, stream>>>(proj_w, wprojbf, 256 * 32);
  mask_prep<<<dim3(64, 8, 8), dim3(256), 0, stream>>>(mask, mfws);
  bias_prep<<<dim3(8, 8), dim3(256), 0, stream>>>(idx, table, bfws);
  qkv_gemm<<<dim3(2304), dim3(256), 0, stream>>>(xbf, wqkvbf, qkv_b, qws, kws, vtws);
  attn_kernel<<<dim3(1536), dim3(512), 0, stream>>>(qws, kws, vtws, mfws, bfws, aows);
  proj_gemm<<<dim3(768), dim3(256), 0, stream>>>(aows, wprojbf, proj_b, out);
}